// Round 2
// baseline (445.163 us; speedup 1.0000x reference)
//
#include <hip/hip_runtime.h>
#include <hip/hip_bf16.h>
#include <stdint.h>

// SynAlign fused kernel: gather+avgpool3 -> bf16 MFMA scores -> dual softmax -> dual PV.
// One workgroup per batch element (grid=256, block=256 = 4 waves).
// Outputs (fp32, concatenated): s[256,128,1024], source_att[256,128,1024],
// at_soft[256,128,128], t[256,128,1024], target_att[256,128,1024], ta_soft[256,128,128]
//
// R1 fix: masks are int32 on device (bool pushed as int), not uint8.

#define SL 128
#define DIM 1024

#define OFF_S     ((size_t)0)
#define OFF_SATT  ((size_t)33554432)
#define OFF_ATSM  ((size_t)67108864)
#define OFF_T     ((size_t)71303168)
#define OFF_TATT  ((size_t)104857600)
#define OFF_TASM  ((size_t)138412032)

typedef short bf16x8 __attribute__((ext_vector_type(8)));
typedef float f32x4 __attribute__((ext_vector_type(4)));
typedef unsigned short u16;

#define CH_LD 40   // chunk row stride in bf16: 32 data + 8 pad (80B rows, 2-way free)
#define SC_LD 136  // score row stride in bf16: 128 data + 8 pad (272B rows)

__device__ __forceinline__ u16 f2bf(float f) {
  union { float f; uint32_t u; } v; v.f = f;
  uint32_t r = (v.u + 0x7FFFu + ((v.u >> 16) & 1u)) >> 16;  // RNE
  return (u16)r;
}
__device__ __forceinline__ float bf2f(u16 h) {
  union { uint32_t u; float f; } v; v.u = ((uint32_t)h) << 16;
  return v.f;
}

__global__ __launch_bounds__(256) void synalign_kernel(
    const int* __restrict__ ssent, const int* __restrict__ tsent,
    const int* __restrict__ smask, const int* __restrict__ tmask,
    const float* __restrict__ semb, const float* __restrict__ temb,
    float* __restrict__ out)
{
  __shared__ u16 t_chunk[SL * CH_LD];   // 10,240 B
  __shared__ u16 s_chunk[SL * CH_LD];   // 10,240 B
  __shared__ u16 score[SL * SC_LD];     // 34,816 B (masked ta_score, bf16)
  __shared__ float rowmax[SL], rowinv[SL], colmax[SL], colinv[SL];
  __shared__ float smaskf[SL], tmaskf[SL];

  const int b = blockIdx.x;
  const int tid = threadIdx.x;
  const int lane = tid & 63;
  const int w = tid >> 6;

  float* s_base    = out + OFF_S    + (size_t)b * SL * DIM;
  float* satt_base = out + OFF_SATT + (size_t)b * SL * DIM;
  float* at_base   = out + OFF_ATSM + (size_t)b * SL * SL;
  float* t_base    = out + OFF_T    + (size_t)b * SL * DIM;
  float* tatt_base = out + OFF_TATT + (size_t)b * SL * DIM;
  float* ta_base   = out + OFF_TASM + (size_t)b * SL * SL;

  if (tid < SL) {
    smaskf[tid] = (smask[b * SL + tid] != 0) ? 1.0f : 0.0f;
    tmaskf[tid] = (tmask[b * SL + tid] != 0) ? 1.0f : 0.0f;
  }

  // ---------------- Phase 0: gather + avgpool3 (exact fp32) ----------------
  {
    const float inv3 = 1.0f / 3.0f;
    #pragma unroll 2
    for (int u = 0; u < 2 * SL; ++u) {
      const int side = u >> 7;
      const int l = u & (SL - 1);
      const int* sent = side ? tsent : ssent;
      const float* emb = side ? temb : semb;
      float* dst = side ? t_base : s_base;
      const int t0 = sent[b * SL + l];
      float4 acc = ((const float4*)(emb + (size_t)t0 * DIM))[tid];
      if (l > 0) {
        const int tp = sent[b * SL + l - 1];
        float4 v = ((const float4*)(emb + (size_t)tp * DIM))[tid];
        acc.x += v.x; acc.y += v.y; acc.z += v.z; acc.w += v.w;
      }
      if (l < SL - 1) {
        const int tn = sent[b * SL + l + 1];
        float4 v = ((const float4*)(emb + (size_t)tn * DIM))[tid];
        acc.x += v.x; acc.y += v.y; acc.z += v.z; acc.w += v.w;
      }
      const float sc = (l == 0 || l == SL - 1) ? 0.5f : inv3;
      acc.x *= sc; acc.y *= sc; acc.z *= sc; acc.w *= sc;
      ((float4*)(dst + (size_t)l * DIM))[tid] = acc;
    }
  }
  __syncthreads();

  // ---------------- Phase A: scores via MFMA (ta_score[t][s]) ----------------
  // wave w owns t-rows [32w, 32w+32); acc[mt][nt] tiles the 128x128 score matrix
  f32x4 acc[2][8];
  #pragma unroll
  for (int mt = 0; mt < 2; ++mt)
    #pragma unroll
    for (int nt = 0; nt < 8; ++nt)
      acc[mt][nt] = (f32x4){0.f, 0.f, 0.f, 0.f};

  for (int dk = 0; dk < DIM; dk += 32) {
    __syncthreads();
    // stage t_chunk[128][32] and s_chunk[128][32] as bf16 (coalesced f32x4 loads)
    #pragma unroll
    for (int j = 0; j < 4; ++j) {
      const int idx = tid + j * 256;   // 1024 float4 units per matrix
      const int row = idx >> 3;        // 8 float4 per 32-col row
      const int c4 = idx & 7;
      float4 v = ((const float4*)(t_base + (size_t)row * DIM + dk))[c4];
      u16* d = &t_chunk[row * CH_LD + c4 * 4];
      d[0] = f2bf(v.x); d[1] = f2bf(v.y); d[2] = f2bf(v.z); d[3] = f2bf(v.w);
      float4 v2 = ((const float4*)(s_base + (size_t)row * DIM + dk))[c4];
      u16* d2 = &s_chunk[row * CH_LD + c4 * 4];
      d2[0] = f2bf(v2.x); d2[1] = f2bf(v2.y); d2[2] = f2bf(v2.z); d2[3] = f2bf(v2.w);
    }
    __syncthreads();

    const int colb = (lane >> 4) * 8;
    bf16x8 afr[2], bfr[8];
    #pragma unroll
    for (int mt = 0; mt < 2; ++mt)
      afr[mt] = *(const bf16x8*)&t_chunk[(w * 32 + mt * 16 + (lane & 15)) * CH_LD + colb];
    #pragma unroll
    for (int nt = 0; nt < 8; ++nt)
      bfr[nt] = *(const bf16x8*)&s_chunk[(nt * 16 + (lane & 15)) * CH_LD + colb];
    #pragma unroll
    for (int mt = 0; mt < 2; ++mt)
      #pragma unroll
      for (int nt = 0; nt < 8; ++nt)
        acc[mt][nt] = __builtin_amdgcn_mfma_f32_16x16x32_bf16(afr[mt], bfr[nt], acc[mt][nt], 0, 0, 0);
  }
  __syncthreads();

  // write masked score (bf16) to LDS: D layout col=lane&15, row=(lane>>4)*4+j
  #pragma unroll
  for (int mt = 0; mt < 2; ++mt)
    #pragma unroll
    for (int nt = 0; nt < 8; ++nt) {
      const int coln = nt * 16 + (lane & 15);
      const float sm = smaskf[coln];
      #pragma unroll
      for (int j = 0; j < 4; ++j) {
        const int rowm = w * 32 + mt * 16 + (lane >> 4) * 4 + j;
        const float val = (sm != 0.0f && tmaskf[rowm] != 0.0f) ? acc[mt][nt][j] : -999.0f;
        score[rowm * SC_LD + coln] = f2bf(val);
      }
    }
  __syncthreads();

  // ---------------- Phase B: softmax stats + matrix outputs ----------------
  if (tid < SL) {
    const int r = tid;  // row = t index (softmax over s)
    float mx = -1e30f;
    #pragma unroll 4
    for (int c8 = 0; c8 < 16; ++c8) {
      const uint4 q = *(const uint4*)&score[r * SC_LD + c8 * 8];
      mx = fmaxf(mx, fmaxf(bf2f((u16)(q.x & 0xffff)), bf2f((u16)(q.x >> 16))));
      mx = fmaxf(mx, fmaxf(bf2f((u16)(q.y & 0xffff)), bf2f((u16)(q.y >> 16))));
      mx = fmaxf(mx, fmaxf(bf2f((u16)(q.z & 0xffff)), bf2f((u16)(q.z >> 16))));
      mx = fmaxf(mx, fmaxf(bf2f((u16)(q.w & 0xffff)), bf2f((u16)(q.w >> 16))));
    }
    float sum = 0.0f;
    #pragma unroll 4
    for (int c8 = 0; c8 < 16; ++c8) {
      const uint4 q = *(const uint4*)&score[r * SC_LD + c8 * 8];
      sum += __expf(bf2f((u16)(q.x & 0xffff)) - mx) + __expf(bf2f((u16)(q.x >> 16)) - mx);
      sum += __expf(bf2f((u16)(q.y & 0xffff)) - mx) + __expf(bf2f((u16)(q.y >> 16)) - mx);
      sum += __expf(bf2f((u16)(q.z & 0xffff)) - mx) + __expf(bf2f((u16)(q.z >> 16)) - mx);
      sum += __expf(bf2f((u16)(q.w & 0xffff)) - mx) + __expf(bf2f((u16)(q.w >> 16)) - mx);
    }
    rowmax[r] = mx; rowinv[r] = 1.0f / sum;
  } else {
    const int r = tid - SL;  // column = s index (softmax over t)
    float mx = -1e30f;
    for (int c = 0; c < SL; ++c) mx = fmaxf(mx, bf2f(score[c * SC_LD + r]));
    float sum = 0.0f;
    for (int c = 0; c < SL; ++c) sum += __expf(bf2f(score[c * SC_LD + r]) - mx);
    colmax[r] = mx; colinv[r] = 1.0f / sum;
  }
  __syncthreads();

  // coalesced writes of ta_soft [t][s] and at_soft [s][t]
  for (int idx = tid; idx < SL * SL; idx += 256) {
    const int r = idx >> 7, c = idx & 127;
    ta_base[idx] = __expf(bf2f(score[r * SC_LD + c]) - rowmax[r]) * rowinv[r];
    at_base[idx] = __expf(bf2f(score[c * SC_LD + r]) - colmax[r]) * colinv[r];
  }

  // ---------------- Phase C: PV GEMMs ----------------
  // PV1: source_att[t][d] = sum_s P_ta[t][s] * s_vals[s][d]
  {
    bf16x8 pa[2][4];
    #pragma unroll
    for (int mt = 0; mt < 2; ++mt) {
      const int m = w * 32 + mt * 16 + (lane & 15);
      const float mx = rowmax[m], iv = rowinv[m];
      #pragma unroll
      for (int ks = 0; ks < 4; ++ks) {
        const int k0 = ks * 32 + (lane >> 4) * 8;
        const bf16x8 s8 = *(const bf16x8*)&score[m * SC_LD + k0];
        bf16x8 p;
        #pragma unroll
        for (int i = 0; i < 8; ++i)
          p[i] = (short)f2bf(__expf(bf2f((u16)s8[i]) - mx) * iv);
        pa[mt][ks] = p;
      }
    }
    for (int n0 = 0; n0 < DIM; n0 += 16) {
      f32x4 o[2];
      o[0] = (f32x4){0.f,0.f,0.f,0.f}; o[1] = (f32x4){0.f,0.f,0.f,0.f};
      #pragma unroll
      for (int ks = 0; ks < 4; ++ks) {
        const int kb = ks * 32 + (lane >> 4) * 8;
        const float* sp = s_base + (size_t)kb * DIM + n0 + (lane & 15);
        bf16x8 bv;
        #pragma unroll
        for (int i = 0; i < 8; ++i) bv[i] = (short)f2bf(sp[(size_t)i * DIM]);
        o[0] = __builtin_amdgcn_mfma_f32_16x16x32_bf16(pa[0][ks], bv, o[0], 0, 0, 0);
        o[1] = __builtin_amdgcn_mfma_f32_16x16x32_bf16(pa[1][ks], bv, o[1], 0, 0, 0);
      }
      #pragma unroll
      for (int mt = 0; mt < 2; ++mt) {
        const int rowm = w * 32 + mt * 16 + (lane >> 4) * 4;
        #pragma unroll
        for (int j = 0; j < 4; ++j)
          satt_base[(size_t)(rowm + j) * DIM + n0 + (lane & 15)] = o[mt][j];
      }
    }
  }
  // PV2: target_att[s][d] = sum_t P_at[s][t] * t_vals[t][d]
  {
    bf16x8 pa[2][4];
    #pragma unroll
    for (int mt = 0; mt < 2; ++mt) {
      const int m = w * 32 + mt * 16 + (lane & 15);  // s index
      const float mx = colmax[m], iv = colinv[m];
      #pragma unroll
      for (int ks = 0; ks < 4; ++ks) {
        const int k0 = ks * 32 + (lane >> 4) * 8;
        bf16x8 p;
        #pragma unroll
        for (int i = 0; i < 8; ++i)
          p[i] = (short)f2bf(__expf(bf2f(score[(k0 + i) * SC_LD + m]) - mx) * iv);
        pa[mt][ks] = p;
      }
    }
    for (int n0 = 0; n0 < DIM; n0 += 16) {
      f32x4 o[2];
      o[0] = (f32x4){0.f,0.f,0.f,0.f}; o[1] = (f32x4){0.f,0.f,0.f,0.f};
      #pragma unroll
      for (int ks = 0; ks < 4; ++ks) {
        const int kb = ks * 32 + (lane >> 4) * 8;
        const float* tp = t_base + (size_t)kb * DIM + n0 + (lane & 15);
        bf16x8 bv;
        #pragma unroll
        for (int i = 0; i < 8; ++i) bv[i] = (short)f2bf(tp[(size_t)i * DIM]);
        o[0] = __builtin_amdgcn_mfma_f32_16x16x32_bf16(pa[0][ks], bv, o[0], 0, 0, 0);
        o[1] = __builtin_amdgcn_mfma_f32_16x16x32_bf16(pa[1][ks], bv, o[1], 0, 0, 0);
      }
      #pragma unroll
      for (int mt = 0; mt < 2; ++mt) {
        const int rowm = w * 32 + mt * 16 + (lane >> 4) * 4;
        #pragma unroll
        for (int j = 0; j < 4; ++j)
          tatt_base[(size_t)(rowm + j) * DIM + n0 + (lane & 15)] = o[mt][j];
      }
    }
  }
}

extern "C" void kernel_launch(void* const* d_in, const int* in_sizes, int n_in,
                              void* d_out, int out_size, void* d_ws, size_t ws_size,
                              hipStream_t stream) {
  const int* ssent = (const int*)d_in[0];
  const int* tsent = (const int*)d_in[1];
  const int* smask = (const int*)d_in[2];
  const int* tmask = (const int*)d_in[3];
  const float* semb = (const float*)d_in[4];
  const float* temb = (const float*)d_in[5];
  float* out = (float*)d_out;
  hipLaunchKernelGGL(synalign_kernel, dim3(256), dim3(256), 0, stream,
                     ssent, tsent, smask, tmask, semb, temb, out);
}

// Round 3
// 405.552 us; speedup vs baseline: 1.0977x; 1.0977x over previous
//
#include <hip/hip_runtime.h>
#include <hip/hip_bf16.h>
#include <stdint.h>

// SynAlign, R3: two-kernel split for occupancy/latency-hiding.
//  K1 pool_kernel:  grid 65536 (one block per (side,b,l) output row), gather+avgpool3, exact fp32.
//  K2 align_kernel: grid 512 (one block per (orientation,b)): bf16 MFMA 128x128 score,
//                   row softmax, soft-matrix write, PV GEMM. Orientations are symmetric.
// Outputs (fp32, concat): s, source_att, at_soft, t, target_att, ta_soft

#define SL 128
#define DIM 1024

#define OFF_S     ((size_t)0)
#define OFF_SATT  ((size_t)33554432)
#define OFF_ATSM  ((size_t)67108864)
#define OFF_T     ((size_t)71303168)
#define OFF_TATT  ((size_t)104857600)
#define OFF_TASM  ((size_t)138412032)

typedef short bf16x8 __attribute__((ext_vector_type(8)));
typedef float f32x4 __attribute__((ext_vector_type(4)));
typedef unsigned short u16;

#define CH_LD 40   // chunk row stride in bf16: 32 data + 8 pad
#define SC_LD 136  // score row stride in bf16: 128 data + 8 pad

__device__ __forceinline__ u16 f2bf(float f) {
  union { float f; uint32_t u; } v; v.f = f;
  uint32_t r = (v.u + 0x7FFFu + ((v.u >> 16) & 1u)) >> 16;  // RNE
  return (u16)r;
}
__device__ __forceinline__ float bf2f(u16 h) {
  union { uint32_t u; float f; } v; v.u = ((uint32_t)h) << 16;
  return v.f;
}

// ---------------- K1: gather + avgpool3 ----------------
// one block per output row: bid = side*32768 + b*128 + l ; 256 thr, float4/thread = 1024 floats
__global__ __launch_bounds__(256) void pool_kernel(
    const int* __restrict__ ssent, const int* __restrict__ tsent,
    const float* __restrict__ semb, const float* __restrict__ temb,
    float* __restrict__ out)
{
  const int bid = blockIdx.x;
  const int side = bid >> 15;
  const int bl = bid & 32767;
  const int b = bl >> 7;
  const int l = bl & 127;
  const int tid = threadIdx.x;

  const int* __restrict__ sent = side ? tsent : ssent;
  const float* __restrict__ emb = side ? temb : semb;
  float* __restrict__ dst = out + (side ? OFF_T : OFF_S) + ((size_t)b * SL + l) * DIM;

  const int i1 = sent[b * SL + l];
  float4 acc = ((const float4*)(emb + (size_t)i1 * DIM))[tid];
  if (l > 0) {
    const int i0 = sent[b * SL + l - 1];
    float4 v = ((const float4*)(emb + (size_t)i0 * DIM))[tid];
    acc.x += v.x; acc.y += v.y; acc.z += v.z; acc.w += v.w;
  }
  if (l < SL - 1) {
    const int i2 = sent[b * SL + l + 1];
    float4 v = ((const float4*)(emb + (size_t)i2 * DIM))[tid];
    acc.x += v.x; acc.y += v.y; acc.z += v.z; acc.w += v.w;
  }
  const float sc = (l == 0 || l == SL - 1) ? 0.5f : (1.0f / 3.0f);
  acc.x *= sc; acc.y *= sc; acc.z *= sc; acc.w *= sc;
  ((float4*)dst)[tid] = acc;
}

// ---------------- K2: score + softmax + PV, one orientation per block ----------------
// bid < 256  -> ori 0 (ta): q=t, k/v=s, soft->ta_soft, att->source_att
// bid >= 256 -> ori 1 (at): q=s, k/v=t, soft->at_soft, att->target_att
__global__ __launch_bounds__(256) void align_kernel(
    const int* __restrict__ smask, const int* __restrict__ tmask,
    float* __restrict__ out)
{
  __shared__ u16 a_chunk[SL * CH_LD];   // q rows  (10,240 B)
  __shared__ u16 b_chunk[SL * CH_LD];   // k rows  (10,240 B)
  __shared__ u16 score[SL * SC_LD];     // 34,816 B masked score (bf16)
  __shared__ float rowmax[SL], rowinv[SL];
  __shared__ float maskR[SL], maskC[SL];

  const int bid = blockIdx.x;
  const int ori = bid >> 8;
  const int b = bid & 255;
  const int tid = threadIdx.x;
  const int lane = tid & 63;
  const int w = tid >> 6;

  const float* q_base = out + (ori ? OFF_S : OFF_T) + (size_t)b * SL * DIM;
  const float* v_base = out + (ori ? OFF_T : OFF_S) + (size_t)b * SL * DIM;  // k/v matrix
  float* soft_base    = out + (ori ? OFF_ATSM : OFF_TASM) + (size_t)b * SL * SL;
  float* att_base     = out + (ori ? OFF_TATT : OFF_SATT) + (size_t)b * SL * DIM;
  const int* rmask = ori ? smask : tmask;
  const int* cmask = ori ? tmask : smask;

  if (tid < SL) {
    maskR[tid] = (rmask[b * SL + tid] != 0) ? 1.0f : 0.0f;
  } else {
    maskC[tid - SL] = (cmask[b * SL + (tid - SL)] != 0) ? 1.0f : 0.0f;
  }

  // ---- Phase A: score[q][k] = sum_d q[q][d]*k[k][d], via 16x16x32 bf16 MFMA ----
  f32x4 acc[2][8];
  #pragma unroll
  for (int mt = 0; mt < 2; ++mt)
    #pragma unroll
    for (int nt = 0; nt < 8; ++nt)
      acc[mt][nt] = (f32x4){0.f, 0.f, 0.f, 0.f};

  for (int dk = 0; dk < DIM; dk += 32) {
    __syncthreads();
    #pragma unroll
    for (int j = 0; j < 4; ++j) {
      const int idx = tid + j * 256;   // 1024 float4 units per matrix
      const int row = idx >> 3;
      const int c4 = idx & 7;
      float4 v = ((const float4*)(q_base + (size_t)row * DIM + dk))[c4];
      u16* d = &a_chunk[row * CH_LD + c4 * 4];
      d[0] = f2bf(v.x); d[1] = f2bf(v.y); d[2] = f2bf(v.z); d[3] = f2bf(v.w);
      float4 v2 = ((const float4*)(v_base + (size_t)row * DIM + dk))[c4];
      u16* d2 = &b_chunk[row * CH_LD + c4 * 4];
      d2[0] = f2bf(v2.x); d2[1] = f2bf(v2.y); d2[2] = f2bf(v2.z); d2[3] = f2bf(v2.w);
    }
    __syncthreads();

    const int colb = (lane >> 4) * 8;
    bf16x8 afr[2], bfr[8];
    #pragma unroll
    for (int mt = 0; mt < 2; ++mt)
      afr[mt] = *(const bf16x8*)&a_chunk[(w * 32 + mt * 16 + (lane & 15)) * CH_LD + colb];
    #pragma unroll
    for (int nt = 0; nt < 8; ++nt)
      bfr[nt] = *(const bf16x8*)&b_chunk[(nt * 16 + (lane & 15)) * CH_LD + colb];
    #pragma unroll
    for (int mt = 0; mt < 2; ++mt)
      #pragma unroll
      for (int nt = 0; nt < 8; ++nt)
        acc[mt][nt] = __builtin_amdgcn_mfma_f32_16x16x32_bf16(afr[mt], bfr[nt], acc[mt][nt], 0, 0, 0);
  }
  __syncthreads();

  // masked score -> LDS (bf16). D layout: col=lane&15, row=(lane>>4)*4+j
  #pragma unroll
  for (int mt = 0; mt < 2; ++mt)
    #pragma unroll
    for (int nt = 0; nt < 8; ++nt) {
      const int coln = nt * 16 + (lane & 15);
      const float cm = maskC[coln];
      #pragma unroll
      for (int j = 0; j < 4; ++j) {
        const int rowm = w * 32 + mt * 16 + (lane >> 4) * 4 + j;
        const float val = (cm != 0.0f && maskR[rowm] != 0.0f) ? acc[mt][nt][j] : -999.0f;
        score[rowm * SC_LD + coln] = f2bf(val);
      }
    }
  __syncthreads();

  // ---- Phase B: row softmax stats + soft-matrix write ----
  if (tid < SL) {
    const int r = tid;
    float mx = -1e30f;
    #pragma unroll 4
    for (int c8 = 0; c8 < 16; ++c8) {
      const uint4 q = *(const uint4*)&score[r * SC_LD + c8 * 8];
      mx = fmaxf(mx, fmaxf(bf2f((u16)(q.x & 0xffff)), bf2f((u16)(q.x >> 16))));
      mx = fmaxf(mx, fmaxf(bf2f((u16)(q.y & 0xffff)), bf2f((u16)(q.y >> 16))));
      mx = fmaxf(mx, fmaxf(bf2f((u16)(q.z & 0xffff)), bf2f((u16)(q.z >> 16))));
      mx = fmaxf(mx, fmaxf(bf2f((u16)(q.w & 0xffff)), bf2f((u16)(q.w >> 16))));
    }
    float sum = 0.0f;
    #pragma unroll 4
    for (int c8 = 0; c8 < 16; ++c8) {
      const uint4 q = *(const uint4*)&score[r * SC_LD + c8 * 8];
      sum += __expf(bf2f((u16)(q.x & 0xffff)) - mx) + __expf(bf2f((u16)(q.x >> 16)) - mx);
      sum += __expf(bf2f((u16)(q.y & 0xffff)) - mx) + __expf(bf2f((u16)(q.y >> 16)) - mx);
      sum += __expf(bf2f((u16)(q.z & 0xffff)) - mx) + __expf(bf2f((u16)(q.z >> 16)) - mx);
      sum += __expf(bf2f((u16)(q.w & 0xffff)) - mx) + __expf(bf2f((u16)(q.w >> 16)) - mx);
    }
    rowmax[r] = mx; rowinv[r] = 1.0f / sum;
  }
  __syncthreads();

  for (int idx = tid; idx < SL * SL; idx += 256) {
    const int r = idx >> 7, c = idx & 127;
    soft_base[idx] = __expf(bf2f(score[r * SC_LD + c]) - rowmax[r]) * rowinv[r];
  }

  // ---- Phase C: att[q][d] = sum_k P[q][k] * v[k][d] ----
  bf16x8 pa[2][4];
  #pragma unroll
  for (int mt = 0; mt < 2; ++mt) {
    const int m = w * 32 + mt * 16 + (lane & 15);
    const float mx = rowmax[m], iv = rowinv[m];
    #pragma unroll
    for (int ks = 0; ks < 4; ++ks) {
      const int k0 = ks * 32 + (lane >> 4) * 8;
      const bf16x8 s8 = *(const bf16x8*)&score[m * SC_LD + k0];
      bf16x8 p;
      #pragma unroll
      for (int i = 0; i < 8; ++i)
        p[i] = (short)f2bf(__expf(bf2f((u16)s8[i]) - mx) * iv);
      pa[mt][ks] = p;
    }
  }
  for (int n0 = 0; n0 < DIM; n0 += 16) {
    f32x4 o[2];
    o[0] = (f32x4){0.f,0.f,0.f,0.f}; o[1] = (f32x4){0.f,0.f,0.f,0.f};
    #pragma unroll
    for (int ks = 0; ks < 4; ++ks) {
      const int kb = ks * 32 + (lane >> 4) * 8;
      const float* vp = v_base + (size_t)kb * DIM + n0 + (lane & 15);
      bf16x8 bv;
      #pragma unroll
      for (int i = 0; i < 8; ++i) bv[i] = (short)f2bf(vp[(size_t)i * DIM]);
      o[0] = __builtin_amdgcn_mfma_f32_16x16x32_bf16(pa[0][ks], bv, o[0], 0, 0, 0);
      o[1] = __builtin_amdgcn_mfma_f32_16x16x32_bf16(pa[1][ks], bv, o[1], 0, 0, 0);
    }
    #pragma unroll
    for (int mt = 0; mt < 2; ++mt) {
      const int rowm = w * 32 + mt * 16 + (lane >> 4) * 4;
      #pragma unroll
      for (int j = 0; j < 4; ++j)
        att_base[(size_t)(rowm + j) * DIM + n0 + (lane & 15)] = o[mt][j];
    }
  }
}

extern "C" void kernel_launch(void* const* d_in, const int* in_sizes, int n_in,
                              void* d_out, int out_size, void* d_ws, size_t ws_size,
                              hipStream_t stream) {
  const int* ssent = (const int*)d_in[0];
  const int* tsent = (const int*)d_in[1];
  const int* smask = (const int*)d_in[2];
  const int* tmask = (const int*)d_in[3];
  const float* semb = (const float*)d_in[4];
  const float* temb = (const float*)d_in[5];
  float* out = (float*)d_out;
  hipLaunchKernelGGL(pool_kernel, dim3(65536), dim3(256), 0, stream,
                     ssent, tsent, semb, temb, out);
  hipLaunchKernelGGL(align_kernel, dim3(512), dim3(256), 0, stream,
                     smask, tmask, out);
}

// Round 4
// 368.664 us; speedup vs baseline: 1.2075x; 1.1001x over previous
//
#include <hip/hip_runtime.h>
#include <hip/hip_bf16.h>
#include <stdint.h>

// SynAlign R4: three-kernel split, work-proportional grids.
//  K1 pool_kernel  : 65536 blocks, gather+avgpool3, exact fp32 (validated).
//  K2 score_kernel : 256 blocks x 512 thr, one block per batch. Score computed ONCE
//                    (at = masked ta^T), row+col softmax, writes ta_soft & at_soft.
//  K3 pv_kernel    : 4096 blocks (ori x batch x 8 n-tiles) x 256 thr. att = P @ V,
//                    A restaged bf16 from soft matrix (L3-hot), B = V^T tile in LDS.

#define SL 128
#define DIM 1024

#define OFF_S     ((size_t)0)
#define OFF_SATT  ((size_t)33554432)
#define OFF_ATSM  ((size_t)67108864)
#define OFF_T     ((size_t)71303168)
#define OFF_TATT  ((size_t)104857600)
#define OFF_TASM  ((size_t)138412032)

typedef short bf16x8 __attribute__((ext_vector_type(8)));
typedef float f32x4 __attribute__((ext_vector_type(4)));
typedef unsigned short u16;

#define CH_LD 40   // chunk row stride (bf16): 32 data + 8 pad
#define SC_LD 136  // score / V^T row stride (bf16): 128 data + 8 pad

__device__ __forceinline__ u16 f2bf(float f) {
  union { float f; uint32_t u; } v; v.f = f;
  uint32_t r = (v.u + 0x7FFFu + ((v.u >> 16) & 1u)) >> 16;  // RNE
  return (u16)r;
}
__device__ __forceinline__ float bf2f(u16 h) {
  union { uint32_t u; float f; } v; v.u = ((uint32_t)h) << 16;
  return v.f;
}

// ---------------- K1: gather + avgpool3 ----------------
__global__ __launch_bounds__(256) void pool_kernel(
    const int* __restrict__ ssent, const int* __restrict__ tsent,
    const float* __restrict__ semb, const float* __restrict__ temb,
    float* __restrict__ out)
{
  const int bid = blockIdx.x;
  const int side = bid >> 15;
  const int bl = bid & 32767;
  const int b = bl >> 7;
  const int l = bl & 127;
  const int tid = threadIdx.x;

  const int* __restrict__ sent = side ? tsent : ssent;
  const float* __restrict__ emb = side ? temb : semb;
  float* __restrict__ dst = out + (side ? OFF_T : OFF_S) + ((size_t)b * SL + l) * DIM;

  const int i1 = sent[b * SL + l];
  float4 acc = ((const float4*)(emb + (size_t)i1 * DIM))[tid];
  if (l > 0) {
    const int i0 = sent[b * SL + l - 1];
    float4 v = ((const float4*)(emb + (size_t)i0 * DIM))[tid];
    acc.x += v.x; acc.y += v.y; acc.z += v.z; acc.w += v.w;
  }
  if (l < SL - 1) {
    const int i2 = sent[b * SL + l + 1];
    float4 v = ((const float4*)(emb + (size_t)i2 * DIM))[tid];
    acc.x += v.x; acc.y += v.y; acc.z += v.z; acc.w += v.w;
  }
  const float sc = (l == 0 || l == SL - 1) ? 0.5f : (1.0f / 3.0f);
  acc.x *= sc; acc.y *= sc; acc.z *= sc; acc.w *= sc;
  ((float4*)dst)[tid] = acc;
}

// ---------------- K2: score (once) + dual softmax ----------------
// one block per batch; 512 threads = 8 waves, wave w owns score rows [16w,16w+16)
__global__ __launch_bounds__(512) void score_kernel(
    const int* __restrict__ smask, const int* __restrict__ tmask,
    float* __restrict__ out)
{
  __shared__ u16 a_chunk[SL * CH_LD];   // t rows
  __shared__ u16 b_chunk[SL * CH_LD];   // s rows
  __shared__ u16 score[SL * SC_LD];     // masked ta_score[t][s], bf16
  __shared__ float rowmax[SL], rowinv[SL], colmax[SL], colinv[SL];
  __shared__ float maskT[SL], maskS[SL];

  const int b = blockIdx.x;
  const int tid = threadIdx.x;
  const int lane = tid & 63;
  const int w = tid >> 6;

  const float* t_base = out + OFF_T + (size_t)b * SL * DIM;
  const float* s_base = out + OFF_S + (size_t)b * SL * DIM;
  float* ta_base = out + OFF_TASM + (size_t)b * SL * SL;
  float* at_base = out + OFF_ATSM + (size_t)b * SL * SL;

  if (tid < SL) maskT[tid] = (tmask[b * SL + tid] != 0) ? 1.0f : 0.0f;
  else if (tid < 2 * SL) maskS[tid - SL] = (smask[b * SL + (tid - SL)] != 0) ? 1.0f : 0.0f;

  f32x4 acc[8];
  #pragma unroll
  for (int nt = 0; nt < 8; ++nt) acc[nt] = (f32x4){0.f, 0.f, 0.f, 0.f};

  for (int dk = 0; dk < DIM; dk += 32) {
    __syncthreads();
    #pragma unroll
    for (int j = 0; j < 2; ++j) {
      const int idx = tid + j * 512;   // 1024 float4 units per matrix
      const int row = idx >> 3;
      const int c4 = idx & 7;
      float4 v = ((const float4*)(t_base + (size_t)row * DIM + dk))[c4];
      u16* d = &a_chunk[row * CH_LD + c4 * 4];
      d[0] = f2bf(v.x); d[1] = f2bf(v.y); d[2] = f2bf(v.z); d[3] = f2bf(v.w);
      float4 v2 = ((const float4*)(s_base + (size_t)row * DIM + dk))[c4];
      u16* d2 = &b_chunk[row * CH_LD + c4 * 4];
      d2[0] = f2bf(v2.x); d2[1] = f2bf(v2.y); d2[2] = f2bf(v2.z); d2[3] = f2bf(v2.w);
    }
    __syncthreads();

    const int colb = (lane >> 4) * 8;
    const bf16x8 afr = *(const bf16x8*)&a_chunk[(w * 16 + (lane & 15)) * CH_LD + colb];
    #pragma unroll
    for (int nt = 0; nt < 8; ++nt) {
      const bf16x8 bfr = *(const bf16x8*)&b_chunk[(nt * 16 + (lane & 15)) * CH_LD + colb];
      acc[nt] = __builtin_amdgcn_mfma_f32_16x16x32_bf16(afr, bfr, acc[nt], 0, 0, 0);
    }
  }
  __syncthreads();

  // masked score -> LDS. D layout: col=lane&15, row=(lane>>4)*4+j (tile base 16w)
  #pragma unroll
  for (int nt = 0; nt < 8; ++nt) {
    const int coln = nt * 16 + (lane & 15);
    const float cm = maskS[coln];
    #pragma unroll
    for (int j = 0; j < 4; ++j) {
      const int rowm = w * 16 + (lane >> 4) * 4 + j;
      const float val = (cm != 0.0f && maskT[rowm] != 0.0f) ? acc[nt][j] : -999.0f;
      score[rowm * SC_LD + coln] = f2bf(val);
    }
  }
  __syncthreads();

  if (tid < SL) {            // row softmax (over s)
    const int r = tid;
    float mx = -1e30f;
    #pragma unroll 4
    for (int c8 = 0; c8 < 16; ++c8) {
      const uint4 q = *(const uint4*)&score[r * SC_LD + c8 * 8];
      mx = fmaxf(mx, fmaxf(bf2f((u16)(q.x & 0xffff)), bf2f((u16)(q.x >> 16))));
      mx = fmaxf(mx, fmaxf(bf2f((u16)(q.y & 0xffff)), bf2f((u16)(q.y >> 16))));
      mx = fmaxf(mx, fmaxf(bf2f((u16)(q.z & 0xffff)), bf2f((u16)(q.z >> 16))));
      mx = fmaxf(mx, fmaxf(bf2f((u16)(q.w & 0xffff)), bf2f((u16)(q.w >> 16))));
    }
    float sum = 0.0f;
    #pragma unroll 4
    for (int c8 = 0; c8 < 16; ++c8) {
      const uint4 q = *(const uint4*)&score[r * SC_LD + c8 * 8];
      sum += __expf(bf2f((u16)(q.x & 0xffff)) - mx) + __expf(bf2f((u16)(q.x >> 16)) - mx);
      sum += __expf(bf2f((u16)(q.y & 0xffff)) - mx) + __expf(bf2f((u16)(q.y >> 16)) - mx);
      sum += __expf(bf2f((u16)(q.z & 0xffff)) - mx) + __expf(bf2f((u16)(q.z >> 16)) - mx);
      sum += __expf(bf2f((u16)(q.w & 0xffff)) - mx) + __expf(bf2f((u16)(q.w >> 16)) - mx);
    }
    rowmax[r] = mx; rowinv[r] = 1.0f / sum;
  } else if (tid >= 256 && tid < 256 + SL) {   // column softmax (over t)
    const int r = tid - 256;
    float mx = -1e30f;
    for (int c = 0; c < SL; ++c) mx = fmaxf(mx, bf2f(score[c * SC_LD + r]));
    float sum = 0.0f;
    for (int c = 0; c < SL; ++c) sum += __expf(bf2f(score[c * SC_LD + r]) - mx);
    colmax[r] = mx; colinv[r] = 1.0f / sum;
  }
  __syncthreads();

  for (int idx = tid; idx < SL * SL; idx += 512) {
    const int r = idx >> 7, c = idx & 127;
    ta_base[idx] = __expf(bf2f(score[r * SC_LD + c]) - rowmax[r]) * rowinv[r];
    at_base[idx] = __expf(bf2f(score[c * SC_LD + r]) - colmax[r]) * colinv[r];
  }
}

// ---------------- K3: PV GEMM ----------------
// bid = ori*2048 + b*8 + ntile ; 256 thr = 4 waves, wave w owns rows [32w,32w+32)
__global__ __launch_bounds__(256) void pv_kernel(float* __restrict__ out)
{
  __shared__ u16 vt_lds[SL * SC_LD];    // V^T tile [n][k], bf16 (34,816 B)
  __shared__ u16 a_chunk[SL * CH_LD];   // P chunk [m][32k] (10,240 B)

  const int bid = blockIdx.x;
  const int ntile = bid & 7;
  const int b = (bid >> 3) & 255;
  const int ori = bid >> 11;
  const int tid = threadIdx.x;
  const int lane = tid & 63;
  const int w = tid >> 6;

  const float* p_base = out + (ori ? OFF_ATSM : OFF_TASM) + (size_t)b * SL * SL;
  const float* v_base = out + (ori ? OFF_T : OFF_S) + (size_t)b * SL * DIM + ntile * 128;
  float* att_base = out + (ori ? OFF_TATT : OFF_SATT) + (size_t)b * SL * DIM + ntile * 128;

  // stage V^T tile: read V[k][n0:n0+128] coalesced, write transposed [n][k]
  #pragma unroll
  for (int j = 0; j < 16; ++j) {
    const int idx = tid + j * 256;   // 4096 float4 units
    const int k = idx >> 5;
    const int c4 = idx & 31;
    float4 v = ((const float4*)(v_base + (size_t)k * DIM))[c4];
    const int n = c4 * 4;
    vt_lds[(n + 0) * SC_LD + k] = f2bf(v.x);
    vt_lds[(n + 1) * SC_LD + k] = f2bf(v.y);
    vt_lds[(n + 2) * SC_LD + k] = f2bf(v.z);
    vt_lds[(n + 3) * SC_LD + k] = f2bf(v.w);
  }

  f32x4 acc[2][8];
  #pragma unroll
  for (int mt = 0; mt < 2; ++mt)
    #pragma unroll
    for (int nt = 0; nt < 8; ++nt)
      acc[mt][nt] = (f32x4){0.f, 0.f, 0.f, 0.f};

  for (int ks = 0; ks < 4; ++ks) {
    __syncthreads();   // iter 0: covers vt_lds staging; later: protects a_chunk reuse
    #pragma unroll
    for (int j = 0; j < 4; ++j) {
      const int idx = tid + j * 256;   // 1024 float4 units
      const int row = idx >> 3;
      const int c4 = idx & 7;
      float4 v = ((const float4*)(p_base + (size_t)row * SL + ks * 32))[c4];
      u16* d = &a_chunk[row * CH_LD + c4 * 4];
      d[0] = f2bf(v.x); d[1] = f2bf(v.y); d[2] = f2bf(v.z); d[3] = f2bf(v.w);
    }
    __syncthreads();

    const int colb = (lane >> 4) * 8;
    bf16x8 afr[2];
    afr[0] = *(const bf16x8*)&a_chunk[(w * 32 + (lane & 15)) * CH_LD + colb];
    afr[1] = *(const bf16x8*)&a_chunk[(w * 32 + 16 + (lane & 15)) * CH_LD + colb];
    #pragma unroll
    for (int nt = 0; nt < 8; ++nt) {
      const bf16x8 bfr = *(const bf16x8*)&vt_lds[(nt * 16 + (lane & 15)) * SC_LD + ks * 32 + colb];
      acc[0][nt] = __builtin_amdgcn_mfma_f32_16x16x32_bf16(afr[0], bfr, acc[0][nt], 0, 0, 0);
      acc[1][nt] = __builtin_amdgcn_mfma_f32_16x16x32_bf16(afr[1], bfr, acc[1][nt], 0, 0, 0);
    }
  }

  #pragma unroll
  for (int mt = 0; mt < 2; ++mt)
    #pragma unroll
    for (int nt = 0; nt < 8; ++nt) {
      const int rowm = w * 32 + mt * 16 + (lane >> 4) * 4;
      #pragma unroll
      for (int j = 0; j < 4; ++j)
        att_base[(size_t)(rowm + j) * DIM + nt * 16 + (lane & 15)] = acc[mt][nt][j];
    }
}

extern "C" void kernel_launch(void* const* d_in, const int* in_sizes, int n_in,
                              void* d_out, int out_size, void* d_ws, size_t ws_size,
                              hipStream_t stream) {
  const int* ssent = (const int*)d_in[0];
  const int* tsent = (const int*)d_in[1];
  const int* smask = (const int*)d_in[2];
  const int* tmask = (const int*)d_in[3];
  const float* semb = (const float*)d_in[4];
  const float* temb = (const float*)d_in[5];
  float* out = (float*)d_out;
  hipLaunchKernelGGL(pool_kernel, dim3(65536), dim3(256), 0, stream,
                     ssent, tsent, semb, temb, out);
  hipLaunchKernelGGL(score_kernel, dim3(256), dim3(512), 0, stream,
                     smask, tmask, out);
  hipLaunchKernelGGL(pv_kernel, dim3(4096), dim3(256), 0, stream, out);
}

// Round 5
// 305.964 us; speedup vs baseline: 1.4550x; 1.2049x over previous
//
#include <hip/hip_runtime.h>
#include <hip/hip_bf16.h>
#include <stdint.h>

// SynAlign R5:
//  K1 pool_kernel : 65536 blocks (XCD-swizzled), gather+avgpool3 fp32 + bf16 sidecar to ws.
//  K2 score_kernel: 256 blocks x 512 thr. Score once (MFMA), parallel 4-way row+col
//                   softmax stats, writes ta_soft & at_soft.
//  K3 pv_kernel   : 4096 blocks x 256 thr. att = P @ V. A-frags direct from global P
//                   (L3-hot), V^T staged once in LDS (k-in-lane, 8-way), 1 barrier.

#define SL 128
#define DIM 1024

#define OFF_S     ((size_t)0)
#define OFF_SATT  ((size_t)33554432)
#define OFF_ATSM  ((size_t)67108864)
#define OFF_T     ((size_t)71303168)
#define OFF_TATT  ((size_t)104857600)
#define OFF_TASM  ((size_t)138412032)
#define SIDE_ELEMS ((size_t)33554432)          // bf16 sidecar elems per side
#define WS_NEEDED  ((size_t)134217728)         // 2 sides * 33.5M * 2B

typedef short bf16x8 __attribute__((ext_vector_type(8)));
typedef float f32x4 __attribute__((ext_vector_type(4)));
typedef unsigned short u16;

#define CH_LD 40   // K2 chunk row stride (bf16): 32 data + 8 pad
#define SC_LD 136  // score row stride (bf16): 128 data + 8 pad
#define VT_LD 136  // K3 V^T row stride (bf16)

__device__ __forceinline__ u16 f2bf(float f) {
  union { float f; uint32_t u; } v; v.f = f;
  uint32_t r = (v.u + 0x7FFFu + ((v.u >> 16) & 1u)) >> 16;  // RNE
  return (u16)r;
}
__device__ __forceinline__ float bf2f(u16 h) {
  union { uint32_t u; float f; } v; v.u = ((uint32_t)h) << 16;
  return v.f;
}

// ---------------- K1: gather + avgpool3 (+ bf16 sidecar) ----------------
__global__ __launch_bounds__(256) void pool_kernel(
    const int* __restrict__ ssent, const int* __restrict__ tsent,
    const float* __restrict__ semb, const float* __restrict__ temb,
    float* __restrict__ out, u16* __restrict__ ws16, int use_ws)
{
  const int raw = blockIdx.x;
  const int bid = (raw & 7) * 8192 + (raw >> 3);   // XCD swizzle (bijective: 65536%8==0)
  const int side = bid >> 15;
  const int bl = bid & 32767;
  const int b = bl >> 7;
  const int l = bl & 127;
  const int tid = threadIdx.x;

  const int* __restrict__ sent = side ? tsent : ssent;
  const float* __restrict__ emb = side ? temb : semb;
  float* __restrict__ dst = out + (side ? OFF_T : OFF_S) + ((size_t)b * SL + l) * DIM;

  const int i1 = sent[b * SL + l];
  float4 acc = ((const float4*)(emb + (size_t)i1 * DIM))[tid];
  if (l > 0) {
    const int i0 = sent[b * SL + l - 1];
    float4 v = ((const float4*)(emb + (size_t)i0 * DIM))[tid];
    acc.x += v.x; acc.y += v.y; acc.z += v.z; acc.w += v.w;
  }
  if (l < SL - 1) {
    const int i2 = sent[b * SL + l + 1];
    float4 v = ((const float4*)(emb + (size_t)i2 * DIM))[tid];
    acc.x += v.x; acc.y += v.y; acc.z += v.z; acc.w += v.w;
  }
  const float sc = (l == 0 || l == SL - 1) ? 0.5f : (1.0f / 3.0f);
  acc.x *= sc; acc.y *= sc; acc.z *= sc; acc.w *= sc;
  ((float4*)dst)[tid] = acc;
  if (use_ws) {
    ushort4 h;
    h.x = f2bf(acc.x); h.y = f2bf(acc.y); h.z = f2bf(acc.z); h.w = f2bf(acc.w);
    u16* d16 = ws16 + (side ? SIDE_ELEMS : 0) + ((size_t)b * SL + l) * DIM;
    ((ushort4*)d16)[tid] = h;
  }
}

// ---------------- K2: score (once) + dual softmax ----------------
__global__ __launch_bounds__(512) void score_kernel(
    const int* __restrict__ smask, const int* __restrict__ tmask,
    float* __restrict__ out, const u16* __restrict__ ws16, int use_ws)
{
  __shared__ __align__(16) u16 a_chunk[SL * CH_LD];   // t rows
  __shared__ __align__(16) u16 b_chunk[SL * CH_LD];   // s rows
  __shared__ __align__(16) u16 score[SL * SC_LD];     // masked ta_score[t][s]
  __shared__ float part[2][4][SL];                    // 0=row,1=col partials
  __shared__ float rowmax[SL], rowinv[SL], colmax[SL], colinv[SL];
  __shared__ float maskT[SL], maskS[SL];

  const int b = blockIdx.x;
  const int tid = threadIdx.x;
  const int lane = tid & 63;
  const int w = tid >> 6;

  const float* t_base = out + OFF_T + (size_t)b * SL * DIM;
  const float* s_base = out + OFF_S + (size_t)b * SL * DIM;
  float* ta_base = out + OFF_TASM + (size_t)b * SL * SL;
  float* at_base = out + OFF_ATSM + (size_t)b * SL * SL;

  if (tid < SL) maskT[tid] = (tmask[b * SL + tid] != 0) ? 1.0f : 0.0f;
  else if (tid < 2 * SL) maskS[tid - SL] = (smask[b * SL + (tid - SL)] != 0) ? 1.0f : 0.0f;

  f32x4 acc[8];
  #pragma unroll
  for (int nt = 0; nt < 8; ++nt) acc[nt] = (f32x4){0.f, 0.f, 0.f, 0.f};

  for (int dk = 0; dk < DIM; dk += 32) {
    __syncthreads();
    #pragma unroll
    for (int j = 0; j < 2; ++j) {
      const int idx = tid + j * 512;           // [0,1024): mat(2) x row(128) x chunk(4)
      const int mat = idx >> 9;                // 0 = t -> a_chunk, 1 = s -> b_chunk
      const int u = idx & 511;
      const int row = u >> 2;
      const int c = u & 3;
      u16* dst = (mat ? b_chunk : a_chunk) + row * CH_LD + c * 8;
      if (use_ws) {
        const u16* src = ws16 + (mat ? (size_t)0 : SIDE_ELEMS)
                       + ((size_t)b * SL + row) * DIM + dk + c * 8;
        *(uint4*)dst = *(const uint4*)src;
      } else {
        const float* src = (mat ? s_base : t_base) + (size_t)row * DIM + dk + c * 8;
        float4 v0 = ((const float4*)src)[0];
        float4 v1 = ((const float4*)src)[1];
        bf16x8 h;
        h[0] = (short)f2bf(v0.x); h[1] = (short)f2bf(v0.y);
        h[2] = (short)f2bf(v0.z); h[3] = (short)f2bf(v0.w);
        h[4] = (short)f2bf(v1.x); h[5] = (short)f2bf(v1.y);
        h[6] = (short)f2bf(v1.z); h[7] = (short)f2bf(v1.w);
        *(bf16x8*)dst = h;
      }
    }
    __syncthreads();

    const int colb = (lane >> 4) * 8;
    const bf16x8 afr = *(const bf16x8*)&a_chunk[(w * 16 + (lane & 15)) * CH_LD + colb];
    #pragma unroll
    for (int nt = 0; nt < 8; ++nt) {
      const bf16x8 bfr = *(const bf16x8*)&b_chunk[(nt * 16 + (lane & 15)) * CH_LD + colb];
      acc[nt] = __builtin_amdgcn_mfma_f32_16x16x32_bf16(afr, bfr, acc[nt], 0, 0, 0);
    }
  }
  __syncthreads();

  // masked score -> LDS. D layout: col=lane&15, row=(lane>>4)*4+j (tile base 16w)
  #pragma unroll
  for (int nt = 0; nt < 8; ++nt) {
    const int coln = nt * 16 + (lane & 15);
    const float cm = maskS[coln];
    #pragma unroll
    for (int j = 0; j < 4; ++j) {
      const int rowm = w * 16 + (lane >> 4) * 4 + j;
      const float val = (cm != 0.0f && maskT[rowm] != 0.0f) ? acc[nt][j] : -999.0f;
      score[rowm * SC_LD + coln] = f2bf(val);
    }
  }
  __syncthreads();

  // ---- parallel 4-way softmax stats ----
  const int rc = tid & 127;       // row (for row-stats) / col (for col-stats)
  const int q = tid >> 7;         // quarter 0..3
  {
    float mx = -1e30f;
    #pragma unroll
    for (int c8 = 0; c8 < 4; ++c8) {
      const uint4 v = *(const uint4*)&score[rc * SC_LD + q * 32 + c8 * 8];
      mx = fmaxf(mx, fmaxf(bf2f((u16)(v.x & 0xffff)), bf2f((u16)(v.x >> 16))));
      mx = fmaxf(mx, fmaxf(bf2f((u16)(v.y & 0xffff)), bf2f((u16)(v.y >> 16))));
      mx = fmaxf(mx, fmaxf(bf2f((u16)(v.z & 0xffff)), bf2f((u16)(v.z >> 16))));
      mx = fmaxf(mx, fmaxf(bf2f((u16)(v.w & 0xffff)), bf2f((u16)(v.w >> 16))));
    }
    part[0][q][rc] = mx;
    float mc = -1e30f;
    #pragma unroll 8
    for (int r = q * 32; r < q * 32 + 32; ++r)
      mc = fmaxf(mc, bf2f(score[r * SC_LD + rc]));
    part[1][q][rc] = mc;
  }
  __syncthreads();
  if (tid < SL) {
    rowmax[tid] = fmaxf(fmaxf(part[0][0][tid], part[0][1][tid]),
                        fmaxf(part[0][2][tid], part[0][3][tid]));
  } else if (tid < 2 * SL) {
    const int c = tid - SL;
    colmax[c] = fmaxf(fmaxf(part[1][0][c], part[1][1][c]),
                      fmaxf(part[1][2][c], part[1][3][c]));
  }
  __syncthreads();
  {
    const float mR = rowmax[rc];
    float sm = 0.0f;
    #pragma unroll
    for (int c8 = 0; c8 < 4; ++c8) {
      const uint4 v = *(const uint4*)&score[rc * SC_LD + q * 32 + c8 * 8];
      sm += __expf(bf2f((u16)(v.x & 0xffff)) - mR) + __expf(bf2f((u16)(v.x >> 16)) - mR);
      sm += __expf(bf2f((u16)(v.y & 0xffff)) - mR) + __expf(bf2f((u16)(v.y >> 16)) - mR);
      sm += __expf(bf2f((u16)(v.z & 0xffff)) - mR) + __expf(bf2f((u16)(v.z >> 16)) - mR);
      sm += __expf(bf2f((u16)(v.w & 0xffff)) - mR) + __expf(bf2f((u16)(v.w >> 16)) - mR);
    }
    part[0][q][rc] = sm;
    const float mC = colmax[rc];
    float sc = 0.0f;
    #pragma unroll 8
    for (int r = q * 32; r < q * 32 + 32; ++r)
      sc += __expf(bf2f(score[r * SC_LD + rc]) - mC);
    part[1][q][rc] = sc;
  }
  __syncthreads();
  if (tid < SL) {
    rowinv[tid] = 1.0f / (part[0][0][tid] + part[0][1][tid] + part[0][2][tid] + part[0][3][tid]);
  } else if (tid < 2 * SL) {
    const int c = tid - SL;
    colinv[c] = 1.0f / (part[1][0][c] + part[1][1][c] + part[1][2][c] + part[1][3][c]);
  }
  __syncthreads();

  for (int idx = tid; idx < SL * SL; idx += 512) {
    const int r = idx >> 7, c = idx & 127;
    ta_base[idx] = __expf(bf2f(score[r * SC_LD + c]) - rowmax[r]) * rowinv[r];
    at_base[idx] = __expf(bf2f(score[c * SC_LD + r]) - colmax[r]) * colinv[r];
  }
}

// ---------------- K3: PV GEMM ----------------
// bid = ori*2048 + b*8 + ntile ; 256 thr = 4 waves, wave w owns rows [32w,32w+32)
__global__ __launch_bounds__(256) void pv_kernel(
    float* __restrict__ out, const u16* __restrict__ ws16, int use_ws)
{
  __shared__ __align__(16) u16 vt[SL * VT_LD];   // V^T [n][k], 34,816 B

  const int bid = blockIdx.x;
  const int ntile = bid & 7;
  const int b = (bid >> 3) & 255;
  const int ori = bid >> 11;
  const int tid = threadIdx.x;
  const int lane = tid & 63;
  const int w = tid >> 6;

  const float* p_base = out + (ori ? OFF_ATSM : OFF_TASM) + (size_t)b * SL * SL;
  float* att_base = out + (ori ? OFF_TATT : OFF_SATT) + (size_t)b * SL * DIM + ntile * 128;

  // stage V^T tile (k in lane-low bits -> 8-way LDS write conflicts, not 32)
  #pragma unroll
  for (int j = 0; j < 8; ++j) {
    const int idx = tid + j * 256;            // [0,2048): k_low(16) x oct(16) x k_high(8)
    const int k = (idx & 15) | ((idx >> 8) << 4);
    const int oct = (idx >> 4) & 15;
    if (use_ws) {
      const u16* src = ws16 + (ori ? SIDE_ELEMS : 0)
                     + ((size_t)b * SL + k) * DIM + ntile * 128 + oct * 8;
      uint4 v = *(const uint4*)src;
      const u16* ev = (const u16*)&v;
      #pragma unroll
      for (int i = 0; i < 8; ++i) vt[(oct * 8 + i) * VT_LD + k] = ev[i];
    } else {
      const float* src = out + (ori ? OFF_T : OFF_S)
                       + ((size_t)b * SL + k) * DIM + ntile * 128 + oct * 8;
      float4 v0 = ((const float4*)src)[0];
      float4 v1 = ((const float4*)src)[1];
      vt[(oct * 8 + 0) * VT_LD + k] = f2bf(v0.x);
      vt[(oct * 8 + 1) * VT_LD + k] = f2bf(v0.y);
      vt[(oct * 8 + 2) * VT_LD + k] = f2bf(v0.z);
      vt[(oct * 8 + 3) * VT_LD + k] = f2bf(v0.w);
      vt[(oct * 8 + 4) * VT_LD + k] = f2bf(v1.x);
      vt[(oct * 8 + 5) * VT_LD + k] = f2bf(v1.y);
      vt[(oct * 8 + 6) * VT_LD + k] = f2bf(v1.z);
      vt[(oct * 8 + 7) * VT_LD + k] = f2bf(v1.w);
    }
  }

  // A-fragments (P) direct from global (L3-hot), overlap with staging
  bf16x8 afr[2][4];
  #pragma unroll
  for (int mt = 0; mt < 2; ++mt) {
    const int m = w * 32 + mt * 16 + (lane & 15);
    #pragma unroll
    for (int ks = 0; ks < 4; ++ks) {
      const int k0 = ks * 32 + (lane >> 4) * 8;
      const float* pp = p_base + (size_t)m * SL + k0;
      float4 x0 = ((const float4*)pp)[0];
      float4 x1 = ((const float4*)pp)[1];
      bf16x8 a;
      a[0] = (short)f2bf(x0.x); a[1] = (short)f2bf(x0.y);
      a[2] = (short)f2bf(x0.z); a[3] = (short)f2bf(x0.w);
      a[4] = (short)f2bf(x1.x); a[5] = (short)f2bf(x1.y);
      a[6] = (short)f2bf(x1.z); a[7] = (short)f2bf(x1.w);
      afr[mt][ks] = a;
    }
  }
  __syncthreads();

  f32x4 acc[2][8];
  #pragma unroll
  for (int mt = 0; mt < 2; ++mt)
    #pragma unroll
    for (int nt = 0; nt < 8; ++nt)
      acc[mt][nt] = (f32x4){0.f, 0.f, 0.f, 0.f};

  const int colb = (lane >> 4) * 8;
  #pragma unroll
  for (int ks = 0; ks < 4; ++ks) {
    #pragma unroll
    for (int nt = 0; nt < 8; ++nt) {
      const bf16x8 bfr = *(const bf16x8*)&vt[(nt * 16 + (lane & 15)) * VT_LD + ks * 32 + colb];
      acc[0][nt] = __builtin_amdgcn_mfma_f32_16x16x32_bf16(afr[0][ks], bfr, acc[0][nt], 0, 0, 0);
      acc[1][nt] = __builtin_amdgcn_mfma_f32_16x16x32_bf16(afr[1][ks], bfr, acc[1][nt], 0, 0, 0);
    }
  }

  #pragma unroll
  for (int mt = 0; mt < 2; ++mt)
    #pragma unroll
    for (int nt = 0; nt < 8; ++nt) {
      const int rowm = w * 32 + mt * 16 + (lane >> 4) * 4;
      #pragma unroll
      for (int j = 0; j < 4; ++j)
        att_base[(size_t)(rowm + j) * DIM + nt * 16 + (lane & 15)] = acc[mt][nt][j];
    }
}

extern "C" void kernel_launch(void* const* d_in, const int* in_sizes, int n_in,
                              void* d_out, int out_size, void* d_ws, size_t ws_size,
                              hipStream_t stream) {
  const int* ssent = (const int*)d_in[0];
  const int* tsent = (const int*)d_in[1];
  const int* smask = (const int*)d_in[2];
  const int* tmask = (const int*)d_in[3];
  const float* semb = (const float*)d_in[4];
  const float* temb = (const float*)d_in[5];
  float* out = (float*)d_out;
  u16* ws16 = (u16*)d_ws;
  const int use_ws = (ws_size >= WS_NEEDED) ? 1 : 0;

  hipLaunchKernelGGL(pool_kernel, dim3(65536), dim3(256), 0, stream,
                     ssent, tsent, semb, temb, out, ws16, use_ws);
  hipLaunchKernelGGL(score_kernel, dim3(256), dim3(512), 0, stream,
                     smask, tmask, out, ws16, use_ws);
  hipLaunchKernelGGL(pv_kernel, dim3(4096), dim3(256), 0, stream, out, ws16, use_ws);
}

// Round 6
// 293.492 us; speedup vs baseline: 1.5168x; 1.0425x over previous
//
#include <hip/hip_runtime.h>
#include <hip/hip_bf16.h>
#include <stdint.h>

// SynAlign R6:
//  K1 pool_kernel : 65536 blocks (XCD-swizzled), gather+avgpool3 fp32 + bf16 sidecar to ws.
//  K2 score_kernel: 256 blocks x 512 thr. Register-prefetch double-buffered staging
//                   (global load for chunk c+1 overlaps MFMA of chunk c), score once,
//                   parallel 4-way row+col softmax stats, writes ta_soft & at_soft.
//  K3 pv_kernel   : 4096 blocks (XCD-swizzled so same-b blocks share P via L2),
//                   att = P @ V, V^T staged once in LDS, 1 barrier.

#define SL 128
#define DIM 1024

#define OFF_S     ((size_t)0)
#define OFF_SATT  ((size_t)33554432)
#define OFF_ATSM  ((size_t)67108864)
#define OFF_T     ((size_t)71303168)
#define OFF_TATT  ((size_t)104857600)
#define OFF_TASM  ((size_t)138412032)
#define SIDE_ELEMS ((size_t)33554432)          // bf16 sidecar elems per side
#define WS_NEEDED  ((size_t)134217728)         // 2 sides * 33.5M * 2B

typedef short bf16x8 __attribute__((ext_vector_type(8)));
typedef float f32x4 __attribute__((ext_vector_type(4)));
typedef unsigned short u16;

#define CH_LD 40   // K2 chunk row stride (bf16): 32 data + 8 pad
#define SC_LD 136  // score row stride (bf16): 128 data + 8 pad
#define VT_LD 136  // K3 V^T row stride (bf16)

__device__ __forceinline__ u16 f2bf(float f) {
  union { float f; uint32_t u; } v; v.f = f;
  uint32_t r = (v.u + 0x7FFFu + ((v.u >> 16) & 1u)) >> 16;  // RNE
  return (u16)r;
}
__device__ __forceinline__ float bf2f(u16 h) {
  union { uint32_t u; float f; } v; v.u = ((uint32_t)h) << 16;
  return v.f;
}

// ---------------- K1: gather + avgpool3 (+ bf16 sidecar) ----------------
__global__ __launch_bounds__(256) void pool_kernel(
    const int* __restrict__ ssent, const int* __restrict__ tsent,
    const float* __restrict__ semb, const float* __restrict__ temb,
    float* __restrict__ out, u16* __restrict__ ws16, int use_ws)
{
  const int raw = blockIdx.x;
  const int bid = (raw & 7) * 8192 + (raw >> 3);   // XCD swizzle (bijective: 65536%8==0)
  const int side = bid >> 15;
  const int bl = bid & 32767;
  const int b = bl >> 7;
  const int l = bl & 127;
  const int tid = threadIdx.x;

  const int* __restrict__ sent = side ? tsent : ssent;
  const float* __restrict__ emb = side ? temb : semb;
  float* __restrict__ dst = out + (side ? OFF_T : OFF_S) + ((size_t)b * SL + l) * DIM;

  const int i1 = sent[b * SL + l];
  float4 acc = ((const float4*)(emb + (size_t)i1 * DIM))[tid];
  if (l > 0) {
    const int i0 = sent[b * SL + l - 1];
    float4 v = ((const float4*)(emb + (size_t)i0 * DIM))[tid];
    acc.x += v.x; acc.y += v.y; acc.z += v.z; acc.w += v.w;
  }
  if (l < SL - 1) {
    const int i2 = sent[b * SL + l + 1];
    float4 v = ((const float4*)(emb + (size_t)i2 * DIM))[tid];
    acc.x += v.x; acc.y += v.y; acc.z += v.z; acc.w += v.w;
  }
  const float sc = (l == 0 || l == SL - 1) ? 0.5f : (1.0f / 3.0f);
  acc.x *= sc; acc.y *= sc; acc.z *= sc; acc.w *= sc;
  ((float4*)dst)[tid] = acc;
  if (use_ws) {
    ushort4 h;
    h.x = f2bf(acc.x); h.y = f2bf(acc.y); h.z = f2bf(acc.z); h.w = f2bf(acc.w);
    u16* d16 = ws16 + (side ? SIDE_ELEMS : 0) + ((size_t)b * SL + l) * DIM;
    ((ushort4*)d16)[tid] = h;
  }
}

// ---------------- K2: score (once) + dual softmax ----------------
__global__ __launch_bounds__(512) void score_kernel(
    const int* __restrict__ smask, const int* __restrict__ tmask,
    float* __restrict__ out, const u16* __restrict__ ws16, int use_ws)
{
  __shared__ __align__(16) u16 a_chunk[SL * CH_LD];   // t rows
  __shared__ __align__(16) u16 b_chunk[SL * CH_LD];   // s rows
  __shared__ __align__(16) u16 score[SL * SC_LD];     // masked ta_score[t][s]
  __shared__ float part[2][4][SL];                    // 0=row,1=col partials
  __shared__ float rowmax[SL], rowinv[SL], colmax[SL], colinv[SL];
  __shared__ float maskT[SL], maskS[SL];

  const int b = blockIdx.x;
  const int tid = threadIdx.x;
  const int lane = tid & 63;
  const int w = tid >> 6;

  const float* t_base = out + OFF_T + (size_t)b * SL * DIM;
  const float* s_base = out + OFF_S + (size_t)b * SL * DIM;
  float* ta_base = out + OFF_TASM + (size_t)b * SL * SL;
  float* at_base = out + OFF_ATSM + (size_t)b * SL * SL;

  if (tid < SL) maskT[tid] = (tmask[b * SL + tid] != 0) ? 1.0f : 0.0f;
  else if (tid < 2 * SL) maskS[tid - SL] = (smask[b * SL + (tid - SL)] != 0) ? 1.0f : 0.0f;

  f32x4 acc[8];
  #pragma unroll
  for (int nt = 0; nt < 8; ++nt) acc[nt] = (f32x4){0.f, 0.f, 0.f, 0.f};

  // staging assignment: each thread owns one 8-elem segment per matrix per chunk
  const int srow = tid >> 2;        // 0..127
  const int sc8 = tid & 3;          // 0..3 (8-elem segment within 32-wide chunk)
  const size_t a_src = SIDE_ELEMS + ((size_t)b * SL + srow) * DIM + sc8 * 8;  // t
  const size_t b_src = ((size_t)b * SL + srow) * DIM + sc8 * 8;               // s
  u16* const a_dst = &a_chunk[srow * CH_LD + sc8 * 8];
  u16* const b_dst = &b_chunk[srow * CH_LD + sc8 * 8];

  // prefetch registers
  uint4 ra, rb;                      // ws path
  float4 fa0, fa1, fb0, fb1;         // fallback path

  if (use_ws) {
    ra = *(const uint4*)(ws16 + a_src);
    rb = *(const uint4*)(ws16 + b_src);
  } else {
    const float* ap = t_base + (size_t)srow * DIM + sc8 * 8;
    const float* bp = s_base + (size_t)srow * DIM + sc8 * 8;
    fa0 = ((const float4*)ap)[0]; fa1 = ((const float4*)ap)[1];
    fb0 = ((const float4*)bp)[0]; fb1 = ((const float4*)bp)[1];
  }

  for (int c = 0; c < 32; ++c) {
    // write prefetched chunk c to LDS
    if (use_ws) {
      *(uint4*)a_dst = ra;
      *(uint4*)b_dst = rb;
    } else {
      bf16x8 ha, hb;
      ha[0]=(short)f2bf(fa0.x); ha[1]=(short)f2bf(fa0.y); ha[2]=(short)f2bf(fa0.z); ha[3]=(short)f2bf(fa0.w);
      ha[4]=(short)f2bf(fa1.x); ha[5]=(short)f2bf(fa1.y); ha[6]=(short)f2bf(fa1.z); ha[7]=(short)f2bf(fa1.w);
      hb[0]=(short)f2bf(fb0.x); hb[1]=(short)f2bf(fb0.y); hb[2]=(short)f2bf(fb0.z); hb[3]=(short)f2bf(fb0.w);
      hb[4]=(short)f2bf(fb1.x); hb[5]=(short)f2bf(fb1.y); hb[6]=(short)f2bf(fb1.z); hb[7]=(short)f2bf(fb1.w);
      *(bf16x8*)a_dst = ha;
      *(bf16x8*)b_dst = hb;
    }
    __syncthreads();

    // prefetch chunk c+1 (latency hides under ds_read + MFMA below)
    if (c + 1 < 32) {
      const int dk = (c + 1) * 32;
      if (use_ws) {
        ra = *(const uint4*)(ws16 + a_src + dk);
        rb = *(const uint4*)(ws16 + b_src + dk);
      } else {
        const float* ap = t_base + (size_t)srow * DIM + dk + sc8 * 8;
        const float* bp = s_base + (size_t)srow * DIM + dk + sc8 * 8;
        fa0 = ((const float4*)ap)[0]; fa1 = ((const float4*)ap)[1];
        fb0 = ((const float4*)bp)[0]; fb1 = ((const float4*)bp)[1];
      }
    }

    // consume chunk c
    const int colb = (lane >> 4) * 8;
    const bf16x8 afr = *(const bf16x8*)&a_chunk[(w * 16 + (lane & 15)) * CH_LD + colb];
    #pragma unroll
    for (int nt = 0; nt < 8; ++nt) {
      const bf16x8 bfr = *(const bf16x8*)&b_chunk[(nt * 16 + (lane & 15)) * CH_LD + colb];
      acc[nt] = __builtin_amdgcn_mfma_f32_16x16x32_bf16(afr, bfr, acc[nt], 0, 0, 0);
    }
    __syncthreads();
  }

  // masked score -> LDS. D layout: col=lane&15, row=(lane>>4)*4+j (tile base 16w)
  #pragma unroll
  for (int nt = 0; nt < 8; ++nt) {
    const int coln = nt * 16 + (lane & 15);
    const float cm = maskS[coln];
    #pragma unroll
    for (int j = 0; j < 4; ++j) {
      const int rowm = w * 16 + (lane >> 4) * 4 + j;
      const float val = (cm != 0.0f && maskT[rowm] != 0.0f) ? acc[nt][j] : -999.0f;
      score[rowm * SC_LD + coln] = f2bf(val);
    }
  }
  __syncthreads();

  // ---- parallel 4-way softmax stats ----
  const int rc = tid & 127;       // row (for row-stats) / col (for col-stats)
  const int q = tid >> 7;         // quarter 0..3
  {
    float mx = -1e30f;
    #pragma unroll
    for (int c8 = 0; c8 < 4; ++c8) {
      const uint4 v = *(const uint4*)&score[rc * SC_LD + q * 32 + c8 * 8];
      mx = fmaxf(mx, fmaxf(bf2f((u16)(v.x & 0xffff)), bf2f((u16)(v.x >> 16))));
      mx = fmaxf(mx, fmaxf(bf2f((u16)(v.y & 0xffff)), bf2f((u16)(v.y >> 16))));
      mx = fmaxf(mx, fmaxf(bf2f((u16)(v.z & 0xffff)), bf2f((u16)(v.z >> 16))));
      mx = fmaxf(mx, fmaxf(bf2f((u16)(v.w & 0xffff)), bf2f((u16)(v.w >> 16))));
    }
    part[0][q][rc] = mx;
    float mc = -1e30f;
    #pragma unroll 8
    for (int r = q * 32; r < q * 32 + 32; ++r)
      mc = fmaxf(mc, bf2f(score[r * SC_LD + rc]));
    part[1][q][rc] = mc;
  }
  __syncthreads();
  if (tid < SL) {
    rowmax[tid] = fmaxf(fmaxf(part[0][0][tid], part[0][1][tid]),
                        fmaxf(part[0][2][tid], part[0][3][tid]));
  } else if (tid < 2 * SL) {
    const int c = tid - SL;
    colmax[c] = fmaxf(fmaxf(part[1][0][c], part[1][1][c]),
                      fmaxf(part[1][2][c], part[1][3][c]));
  }
  __syncthreads();
  {
    const float mR = rowmax[rc];
    float sm = 0.0f;
    #pragma unroll
    for (int c8 = 0; c8 < 4; ++c8) {
      const uint4 v = *(const uint4*)&score[rc * SC_LD + q * 32 + c8 * 8];
      sm += __expf(bf2f((u16)(v.x & 0xffff)) - mR) + __expf(bf2f((u16)(v.x >> 16)) - mR);
      sm += __expf(bf2f((u16)(v.y & 0xffff)) - mR) + __expf(bf2f((u16)(v.y >> 16)) - mR);
      sm += __expf(bf2f((u16)(v.z & 0xffff)) - mR) + __expf(bf2f((u16)(v.z >> 16)) - mR);
      sm += __expf(bf2f((u16)(v.w & 0xffff)) - mR) + __expf(bf2f((u16)(v.w >> 16)) - mR);
    }
    part[0][q][rc] = sm;
    const float mC = colmax[rc];
    float sc = 0.0f;
    #pragma unroll 8
    for (int r = q * 32; r < q * 32 + 32; ++r)
      sc += __expf(bf2f(score[r * SC_LD + rc]) - mC);
    part[1][q][rc] = sc;
  }
  __syncthreads();
  if (tid < SL) {
    rowinv[tid] = 1.0f / (part[0][0][tid] + part[0][1][tid] + part[0][2][tid] + part[0][3][tid]);
  } else if (tid < 2 * SL) {
    const int c = tid - SL;
    colinv[c] = 1.0f / (part[1][0][c] + part[1][1][c] + part[1][2][c] + part[1][3][c]);
  }
  __syncthreads();

  for (int idx = tid; idx < SL * SL; idx += 512) {
    const int r = idx >> 7, c = idx & 127;
    ta_base[idx] = __expf(bf2f(score[r * SC_LD + c]) - rowmax[r]) * rowinv[r];
    at_base[idx] = __expf(bf2f(score[c * SC_LD + r]) - colmax[r]) * colinv[r];
  }
}

// ---------------- K3: PV GEMM ----------------
// final bid = ori*2048 + b*8 + ntile ; XCD swizzle so the 8 same-b blocks (shared P)
// land on one XCD's L2. 256 thr = 4 waves, wave w owns rows [32w,32w+32)
__global__ __launch_bounds__(256) void pv_kernel(
    float* __restrict__ out, const u16* __restrict__ ws16, int use_ws)
{
  __shared__ __align__(16) u16 vt[SL * VT_LD];   // V^T [n][k], 34,816 B

  const int raw = blockIdx.x;
  const int bid = (raw & 7) * 512 + (raw >> 3);  // bijective: 4096 % 8 == 0
  const int ntile = bid & 7;
  const int b = (bid >> 3) & 255;
  const int ori = bid >> 11;
  const int tid = threadIdx.x;
  const int lane = tid & 63;
  const int w = tid >> 6;

  const float* p_base = out + (ori ? OFF_ATSM : OFF_TASM) + (size_t)b * SL * SL;
  float* att_base = out + (ori ? OFF_TATT : OFF_SATT) + (size_t)b * SL * DIM + ntile * 128;

  // stage V^T tile (k in lane-low bits -> 8-way LDS write conflicts, not 32)
  #pragma unroll
  for (int j = 0; j < 8; ++j) {
    const int idx = tid + j * 256;            // [0,2048): k_low(16) x oct(16) x k_high(8)
    const int k = (idx & 15) | ((idx >> 8) << 4);
    const int oct = (idx >> 4) & 15;
    if (use_ws) {
      const u16* src = ws16 + (ori ? SIDE_ELEMS : 0)
                     + ((size_t)b * SL + k) * DIM + ntile * 128 + oct * 8;
      uint4 v = *(const uint4*)src;
      const u16* ev = (const u16*)&v;
      #pragma unroll
      for (int i = 0; i < 8; ++i) vt[(oct * 8 + i) * VT_LD + k] = ev[i];
    } else {
      const float* src = out + (ori ? OFF_T : OFF_S)
                       + ((size_t)b * SL + k) * DIM + ntile * 128 + oct * 8;
      float4 v0 = ((const float4*)src)[0];
      float4 v1 = ((const float4*)src)[1];
      vt[(oct * 8 + 0) * VT_LD + k] = f2bf(v0.x);
      vt[(oct * 8 + 1) * VT_LD + k] = f2bf(v0.y);
      vt[(oct * 8 + 2) * VT_LD + k] = f2bf(v0.z);
      vt[(oct * 8 + 3) * VT_LD + k] = f2bf(v0.w);
      vt[(oct * 8 + 4) * VT_LD + k] = f2bf(v1.x);
      vt[(oct * 8 + 5) * VT_LD + k] = f2bf(v1.y);
      vt[(oct * 8 + 6) * VT_LD + k] = f2bf(v1.z);
      vt[(oct * 8 + 7) * VT_LD + k] = f2bf(v1.w);
    }
  }

  // A-fragments (P) direct from global (L2/L3-hot), overlap with staging
  bf16x8 afr[2][4];
  #pragma unroll
  for (int mt = 0; mt < 2; ++mt) {
    const int m = w * 32 + mt * 16 + (lane & 15);
    #pragma unroll
    for (int ks = 0; ks < 4; ++ks) {
      const int k0 = ks * 32 + (lane >> 4) * 8;
      const float* pp = p_base + (size_t)m * SL + k0;
      float4 x0 = ((const float4*)pp)[0];
      float4 x1 = ((const float4*)pp)[1];
      bf16x8 a;
      a[0] = (short)f2bf(x0.x); a[1] = (short)f2bf(x0.y);
      a[2] = (short)f2bf(x0.z); a[3] = (short)f2bf(x0.w);
      a[4] = (short)f2bf(x1.x); a[5] = (short)f2bf(x1.y);
      a[6] = (short)f2bf(x1.z); a[7] = (short)f2bf(x1.w);
      afr[mt][ks] = a;
    }
  }
  __syncthreads();

  f32x4 acc[2][8];
  #pragma unroll
  for (int mt = 0; mt < 2; ++mt)
    #pragma unroll
    for (int nt = 0; nt < 8; ++nt)
      acc[mt][nt] = (f32x4){0.f, 0.f, 0.f, 0.f};

  const int colb = (lane >> 4) * 8;
  #pragma unroll
  for (int ks = 0; ks < 4; ++ks) {
    #pragma unroll
    for (int nt = 0; nt < 8; ++nt) {
      const bf16x8 bfr = *(const bf16x8*)&vt[(nt * 16 + (lane & 15)) * VT_LD + ks * 32 + colb];
      acc[0][nt] = __builtin_amdgcn_mfma_f32_16x16x32_bf16(afr[0][ks], bfr, acc[0][nt], 0, 0, 0);
      acc[1][nt] = __builtin_amdgcn_mfma_f32_16x16x32_bf16(afr[1][ks], bfr, acc[1][nt], 0, 0, 0);
    }
  }

  #pragma unroll
  for (int mt = 0; mt < 2; ++mt)
    #pragma unroll
    for (int nt = 0; nt < 8; ++nt) {
      const int rowm = w * 32 + mt * 16 + (lane >> 4) * 4;
      #pragma unroll
      for (int j = 0; j < 4; ++j)
        att_base[(size_t)(rowm + j) * DIM + nt * 16 + (lane & 15)] = acc[mt][nt][j];
    }
}

extern "C" void kernel_launch(void* const* d_in, const int* in_sizes, int n_in,
                              void* d_out, int out_size, void* d_ws, size_t ws_size,
                              hipStream_t stream) {
  const int* ssent = (const int*)d_in[0];
  const int* tsent = (const int*)d_in[1];
  const int* smask = (const int*)d_in[2];
  const int* tmask = (const int*)d_in[3];
  const float* semb = (const float*)d_in[4];
  const float* temb = (const float*)d_in[5];
  float* out = (float*)d_out;
  u16* ws16 = (u16*)d_ws;
  const int use_ws = (ws_size >= WS_NEEDED) ? 1 : 0;

  hipLaunchKernelGGL(pool_kernel, dim3(65536), dim3(256), 0, stream,
                     ssent, tsent, semb, temb, out, ws16, use_ws);
  hipLaunchKernelGGL(score_kernel, dim3(256), dim3(512), 0, stream,
                     smask, tmask, out, ws16, use_ws);
  hipLaunchKernelGGL(pv_kernel, dim3(4096), dim3(256), 0, stream, out, ws16, use_ws);
}

// Round 7
// 259.047 us; speedup vs baseline: 1.7185x; 1.1330x over previous
//
#include <hip/hip_runtime.h>
#include <hip/hip_bf16.h>
#include <stdint.h>

// SynAlign R7:
//  K1 pool_kernel : 65536 blocks (XCD-swizzled), gather+avgpool3; fp32 outputs via
//                   NONTEMPORAL stores (write-once, keep L3 for embedding tables);
//                   bf16 sidecar (cached, re-read by K2/K3).
//  K2 score_kernel: 256 blocks x 512 thr, reg-prefetch staging, score once, 4-way
//                   parallel row+col softmax; writes soft fp32 (nt) + bf16 P sidecar.
//  K3 pv_kernel   : 4096 blocks (XCD-swizzled), att = P @ V; A-frags = single 16B
//                   loads from bf16 P sidecar; V^T in LDS; att stores nontemporal.

#define SL 128
#define DIM 1024

#define OFF_S     ((size_t)0)
#define OFF_SATT  ((size_t)33554432)
#define OFF_ATSM  ((size_t)67108864)
#define OFF_T     ((size_t)71303168)
#define OFF_TATT  ((size_t)104857600)
#define OFF_TASM  ((size_t)138412032)
#define SIDE_ELEMS ((size_t)33554432)           // bf16 sidecar elems per side
#define PHALF      ((size_t)4194304)            // elems per bf16 soft matrix
#define WS_NEEDED   ((size_t)134217728)         // s/t sidecar bytes
#define WS_P_NEEDED ((size_t)150994944)         // + 2 * 4.19M * 2B for P sidecar

typedef short bf16x8 __attribute__((ext_vector_type(8)));
typedef float f32x4 __attribute__((ext_vector_type(4)));
typedef unsigned short u16;

#define CH_LD 40   // K2 chunk row stride (bf16): 32 data + 8 pad
#define SC_LD 136  // score row stride (bf16): 128 data + 8 pad
#define VT_LD 136  // K3 V^T row stride (bf16)

__device__ __forceinline__ u16 f2bf(float f) {
  union { float f; uint32_t u; } v; v.f = f;
  uint32_t r = (v.u + 0x7FFFu + ((v.u >> 16) & 1u)) >> 16;  // RNE
  return (u16)r;
}
__device__ __forceinline__ float bf2f(u16 h) {
  union { uint32_t u; float f; } v; v.u = ((uint32_t)h) << 16;
  return v.f;
}

// ---------------- K1: gather + avgpool3 (+ bf16 sidecar) ----------------
__global__ __launch_bounds__(256) void pool_kernel(
    const int* __restrict__ ssent, const int* __restrict__ tsent,
    const float* __restrict__ semb, const float* __restrict__ temb,
    float* __restrict__ out, u16* __restrict__ ws16, int use_ws)
{
  const int raw = blockIdx.x;
  const int bid = (raw & 7) * 8192 + (raw >> 3);   // XCD swizzle (bijective: 65536%8==0)
  const int side = bid >> 15;
  const int bl = bid & 32767;
  const int b = bl >> 7;
  const int l = bl & 127;
  const int tid = threadIdx.x;

  const int* __restrict__ sent = side ? tsent : ssent;
  const float* __restrict__ emb = side ? temb : semb;
  float* __restrict__ dst = out + (side ? OFF_T : OFF_S) + ((size_t)b * SL + l) * DIM;

  const int i1 = sent[b * SL + l];
  float4 acc = ((const float4*)(emb + (size_t)i1 * DIM))[tid];
  if (l > 0) {
    const int i0 = sent[b * SL + l - 1];
    float4 v = ((const float4*)(emb + (size_t)i0 * DIM))[tid];
    acc.x += v.x; acc.y += v.y; acc.z += v.z; acc.w += v.w;
  }
  if (l < SL - 1) {
    const int i2 = sent[b * SL + l + 1];
    float4 v = ((const float4*)(emb + (size_t)i2 * DIM))[tid];
    acc.x += v.x; acc.y += v.y; acc.z += v.z; acc.w += v.w;
  }
  const float sc = (l == 0 || l == SL - 1) ? 0.5f : (1.0f / 3.0f);
  acc.x *= sc; acc.y *= sc; acc.z *= sc; acc.w *= sc;
  // fp32 output: write-once, never re-read -> bypass caches, keep L3 for tables
  f32x4 av; av[0] = acc.x; av[1] = acc.y; av[2] = acc.z; av[3] = acc.w;
  __builtin_nontemporal_store(av, ((f32x4*)dst) + tid);
  if (use_ws) {
    ushort4 h;
    h.x = f2bf(acc.x); h.y = f2bf(acc.y); h.z = f2bf(acc.z); h.w = f2bf(acc.w);
    u16* d16 = ws16 + (side ? SIDE_ELEMS : 0) + ((size_t)b * SL + l) * DIM;
    ((ushort4*)d16)[tid] = h;   // cached: re-read by K2/K3
  }
}

// ---------------- K2: score (once) + dual softmax ----------------
__global__ __launch_bounds__(512) void score_kernel(
    const int* __restrict__ smask, const int* __restrict__ tmask,
    float* __restrict__ out, u16* __restrict__ ws16, int use_ws, int use_p16)
{
  __shared__ __align__(16) u16 a_chunk[SL * CH_LD];   // t rows
  __shared__ __align__(16) u16 b_chunk[SL * CH_LD];   // s rows
  __shared__ __align__(16) u16 score[SL * SC_LD];     // masked ta_score[t][s]
  __shared__ float part[2][4][SL];                    // 0=row,1=col partials
  __shared__ float rowmax[SL], rowinv[SL], colmax[SL], colinv[SL];
  __shared__ float maskT[SL], maskS[SL];

  const int b = blockIdx.x;
  const int tid = threadIdx.x;
  const int lane = tid & 63;
  const int w = tid >> 6;

  const float* t_base = out + OFF_T + (size_t)b * SL * DIM;
  const float* s_base = out + OFF_S + (size_t)b * SL * DIM;
  float* ta_base = out + OFF_TASM + (size_t)b * SL * SL;
  float* at_base = out + OFF_ATSM + (size_t)b * SL * SL;
  u16* taP = ws16 + 2 * SIDE_ELEMS + (size_t)b * SL * SL;           // P sidecar slot 0 (ta)
  u16* atP = ws16 + 2 * SIDE_ELEMS + PHALF + (size_t)b * SL * SL;   // slot 1 (at)

  if (tid < SL) maskT[tid] = (tmask[b * SL + tid] != 0) ? 1.0f : 0.0f;
  else if (tid < 2 * SL) maskS[tid - SL] = (smask[b * SL + (tid - SL)] != 0) ? 1.0f : 0.0f;

  f32x4 acc[8];
  #pragma unroll
  for (int nt = 0; nt < 8; ++nt) acc[nt] = (f32x4){0.f, 0.f, 0.f, 0.f};

  // staging assignment: each thread owns one 8-elem segment per matrix per chunk
  const int srow = tid >> 2;        // 0..127
  const int sc8 = tid & 3;          // 0..3
  const size_t a_src = SIDE_ELEMS + ((size_t)b * SL + srow) * DIM + sc8 * 8;  // t
  const size_t b_src = ((size_t)b * SL + srow) * DIM + sc8 * 8;               // s
  u16* const a_dst = &a_chunk[srow * CH_LD + sc8 * 8];
  u16* const b_dst = &b_chunk[srow * CH_LD + sc8 * 8];

  uint4 ra, rb;
  float4 fa0, fa1, fb0, fb1;

  if (use_ws) {
    ra = *(const uint4*)(ws16 + a_src);
    rb = *(const uint4*)(ws16 + b_src);
  } else {
    const float* ap = t_base + (size_t)srow * DIM + sc8 * 8;
    const float* bp = s_base + (size_t)srow * DIM + sc8 * 8;
    fa0 = ((const float4*)ap)[0]; fa1 = ((const float4*)ap)[1];
    fb0 = ((const float4*)bp)[0]; fb1 = ((const float4*)bp)[1];
  }

  for (int c = 0; c < 32; ++c) {
    if (use_ws) {
      *(uint4*)a_dst = ra;
      *(uint4*)b_dst = rb;
    } else {
      bf16x8 ha, hb;
      ha[0]=(short)f2bf(fa0.x); ha[1]=(short)f2bf(fa0.y); ha[2]=(short)f2bf(fa0.z); ha[3]=(short)f2bf(fa0.w);
      ha[4]=(short)f2bf(fa1.x); ha[5]=(short)f2bf(fa1.y); ha[6]=(short)f2bf(fa1.z); ha[7]=(short)f2bf(fa1.w);
      hb[0]=(short)f2bf(fb0.x); hb[1]=(short)f2bf(fb0.y); hb[2]=(short)f2bf(fb0.z); hb[3]=(short)f2bf(fb0.w);
      hb[4]=(short)f2bf(fb1.x); hb[5]=(short)f2bf(fb1.y); hb[6]=(short)f2bf(fb1.z); hb[7]=(short)f2bf(fb1.w);
      *(bf16x8*)a_dst = ha;
      *(bf16x8*)b_dst = hb;
    }
    __syncthreads();

    if (c + 1 < 32) {   // prefetch chunk c+1, hides under ds_read + MFMA
      const int dk = (c + 1) * 32;
      if (use_ws) {
        ra = *(const uint4*)(ws16 + a_src + dk);
        rb = *(const uint4*)(ws16 + b_src + dk);
      } else {
        const float* ap = t_base + (size_t)srow * DIM + dk + sc8 * 8;
        const float* bp = s_base + (size_t)srow * DIM + dk + sc8 * 8;
        fa0 = ((const float4*)ap)[0]; fa1 = ((const float4*)ap)[1];
        fb0 = ((const float4*)bp)[0]; fb1 = ((const float4*)bp)[1];
      }
    }

    const int colb = (lane >> 4) * 8;
    const bf16x8 afr = *(const bf16x8*)&a_chunk[(w * 16 + (lane & 15)) * CH_LD + colb];
    #pragma unroll
    for (int nt = 0; nt < 8; ++nt) {
      const bf16x8 bfr = *(const bf16x8*)&b_chunk[(nt * 16 + (lane & 15)) * CH_LD + colb];
      acc[nt] = __builtin_amdgcn_mfma_f32_16x16x32_bf16(afr, bfr, acc[nt], 0, 0, 0);
    }
    __syncthreads();
  }

  // masked score -> LDS. D layout: col=lane&15, row=(lane>>4)*4+j (tile base 16w)
  #pragma unroll
  for (int nt = 0; nt < 8; ++nt) {
    const int coln = nt * 16 + (lane & 15);
    const float cm = maskS[coln];
    #pragma unroll
    for (int j = 0; j < 4; ++j) {
      const int rowm = w * 16 + (lane >> 4) * 4 + j;
      const float val = (cm != 0.0f && maskT[rowm] != 0.0f) ? acc[nt][j] : -999.0f;
      score[rowm * SC_LD + coln] = f2bf(val);
    }
  }
  __syncthreads();

  // ---- parallel 4-way softmax stats ----
  const int rc = tid & 127;
  const int q = tid >> 7;
  {
    float mx = -1e30f;
    #pragma unroll
    for (int c8 = 0; c8 < 4; ++c8) {
      const uint4 v = *(const uint4*)&score[rc * SC_LD + q * 32 + c8 * 8];
      mx = fmaxf(mx, fmaxf(bf2f((u16)(v.x & 0xffff)), bf2f((u16)(v.x >> 16))));
      mx = fmaxf(mx, fmaxf(bf2f((u16)(v.y & 0xffff)), bf2f((u16)(v.y >> 16))));
      mx = fmaxf(mx, fmaxf(bf2f((u16)(v.z & 0xffff)), bf2f((u16)(v.z >> 16))));
      mx = fmaxf(mx, fmaxf(bf2f((u16)(v.w & 0xffff)), bf2f((u16)(v.w >> 16))));
    }
    part[0][q][rc] = mx;
    float mc = -1e30f;
    #pragma unroll 8
    for (int r = q * 32; r < q * 32 + 32; ++r)
      mc = fmaxf(mc, bf2f(score[r * SC_LD + rc]));
    part[1][q][rc] = mc;
  }
  __syncthreads();
  if (tid < SL) {
    rowmax[tid] = fmaxf(fmaxf(part[0][0][tid], part[0][1][tid]),
                        fmaxf(part[0][2][tid], part[0][3][tid]));
  } else if (tid < 2 * SL) {
    const int c = tid - SL;
    colmax[c] = fmaxf(fmaxf(part[1][0][c], part[1][1][c]),
                      fmaxf(part[1][2][c], part[1][3][c]));
  }
  __syncthreads();
  {
    const float mR = rowmax[rc];
    float sm = 0.0f;
    #pragma unroll
    for (int c8 = 0; c8 < 4; ++c8) {
      const uint4 v = *(const uint4*)&score[rc * SC_LD + q * 32 + c8 * 8];
      sm += __expf(bf2f((u16)(v.x & 0xffff)) - mR) + __expf(bf2f((u16)(v.x >> 16)) - mR);
      sm += __expf(bf2f((u16)(v.y & 0xffff)) - mR) + __expf(bf2f((u16)(v.y >> 16)) - mR);
      sm += __expf(bf2f((u16)(v.z & 0xffff)) - mR) + __expf(bf2f((u16)(v.z >> 16)) - mR);
      sm += __expf(bf2f((u16)(v.w & 0xffff)) - mR) + __expf(bf2f((u16)(v.w >> 16)) - mR);
    }
    part[0][q][rc] = sm;
    const float mC = colmax[rc];
    float sc = 0.0f;
    #pragma unroll 8
    for (int r = q * 32; r < q * 32 + 32; ++r)
      sc += __expf(bf2f(score[r * SC_LD + rc]) - mC);
    part[1][q][rc] = sc;
  }
  __syncthreads();
  if (tid < SL) {
    rowinv[tid] = 1.0f / (part[0][0][tid] + part[0][1][tid] + part[0][2][tid] + part[0][3][tid]);
  } else if (tid < 2 * SL) {
    const int c = tid - SL;
    colinv[c] = 1.0f / (part[1][0][c] + part[1][1][c] + part[1][2][c] + part[1][3][c]);
  }
  __syncthreads();

  for (int idx = tid; idx < SL * SL; idx += 512) {
    const int r = idx >> 7, c = idx & 127;
    const float tv = __expf(bf2f(score[r * SC_LD + c]) - rowmax[r]) * rowinv[r];
    const float av = __expf(bf2f(score[c * SC_LD + r]) - colmax[r]) * colinv[r];
    __builtin_nontemporal_store(tv, &ta_base[idx]);   // final outputs
    __builtin_nontemporal_store(av, &at_base[idx]);
    if (use_p16) {                                     // cached: re-read by K3
      taP[idx] = f2bf(tv);
      atP[idx] = f2bf(av);
    }
  }
}

// ---------------- K3: PV GEMM ----------------
// final bid = ori*2048 + b*8 + ntile ; XCD swizzle so the 8 same-b blocks (shared P)
// land on one XCD's L2. 256 thr = 4 waves, wave w owns rows [32w,32w+32)
__global__ __launch_bounds__(256) void pv_kernel(
    float* __restrict__ out, u16* __restrict__ ws16, int use_ws, int use_p16)
{
  __shared__ __align__(16) u16 vt[SL * VT_LD];   // V^T [n][k], 34,816 B

  const int raw = blockIdx.x;
  const int bid = (raw & 7) * 512 + (raw >> 3);  // bijective: 4096 % 8 == 0
  const int ntile = bid & 7;
  const int b = (bid >> 3) & 255;
  const int ori = bid >> 11;
  const int tid = threadIdx.x;
  const int lane = tid & 63;
  const int w = tid >> 6;

  const float* p_base = out + (ori ? OFF_ATSM : OFF_TASM) + (size_t)b * SL * SL;
  const u16* p16_base = ws16 + 2 * SIDE_ELEMS + (ori ? PHALF : (size_t)0) + (size_t)b * SL * SL;
  float* att_base = out + (ori ? OFF_TATT : OFF_SATT) + (size_t)b * SL * DIM + ntile * 128;

  // stage V^T tile (k in lane-low bits -> 8-way LDS write conflicts, not 32)
  #pragma unroll
  for (int j = 0; j < 8; ++j) {
    const int idx = tid + j * 256;            // [0,2048): k_low(16) x oct(16) x k_high(8)
    const int k = (idx & 15) | ((idx >> 8) << 4);
    const int oct = (idx >> 4) & 15;
    if (use_ws) {
      const u16* src = ws16 + (ori ? SIDE_ELEMS : 0)
                     + ((size_t)b * SL + k) * DIM + ntile * 128 + oct * 8;
      uint4 v = *(const uint4*)src;
      const u16* ev = (const u16*)&v;
      #pragma unroll
      for (int i = 0; i < 8; ++i) vt[(oct * 8 + i) * VT_LD + k] = ev[i];
    } else {
      const float* src = out + (ori ? OFF_T : OFF_S)
                       + ((size_t)b * SL + k) * DIM + ntile * 128 + oct * 8;
      float4 v0 = ((const float4*)src)[0];
      float4 v1 = ((const float4*)src)[1];
      vt[(oct * 8 + 0) * VT_LD + k] = f2bf(v0.x);
      vt[(oct * 8 + 1) * VT_LD + k] = f2bf(v0.y);
      vt[(oct * 8 + 2) * VT_LD + k] = f2bf(v0.z);
      vt[(oct * 8 + 3) * VT_LD + k] = f2bf(v0.w);
      vt[(oct * 8 + 4) * VT_LD + k] = f2bf(v1.x);
      vt[(oct * 8 + 5) * VT_LD + k] = f2bf(v1.y);
      vt[(oct * 8 + 6) * VT_LD + k] = f2bf(v1.z);
      vt[(oct * 8 + 7) * VT_LD + k] = f2bf(v1.w);
    }
  }

  // A-fragments (P): single 16B bf16 loads from sidecar (L3-hot), overlap with staging
  bf16x8 afr[2][4];
  #pragma unroll
  for (int mt = 0; mt < 2; ++mt) {
    const int m = w * 32 + mt * 16 + (lane & 15);
    #pragma unroll
    for (int ks = 0; ks < 4; ++ks) {
      const int k0 = ks * 32 + (lane >> 4) * 8;
      if (use_p16) {
        afr[mt][ks] = *(const bf16x8*)(p16_base + (size_t)m * SL + k0);
      } else {
        const float* pp = p_base + (size_t)m * SL + k0;
        float4 x0 = ((const float4*)pp)[0];
        float4 x1 = ((const float4*)pp)[1];
        bf16x8 a;
        a[0] = (short)f2bf(x0.x); a[1] = (short)f2bf(x0.y);
        a[2] = (short)f2bf(x0.z); a[3] = (short)f2bf(x0.w);
        a[4] = (short)f2bf(x1.x); a[5] = (short)f2bf(x1.y);
        a[6] = (short)f2bf(x1.z); a[7] = (short)f2bf(x1.w);
        afr[mt][ks] = a;
      }
    }
  }
  __syncthreads();

  f32x4 acc[2][8];
  #pragma unroll
  for (int mt = 0; mt < 2; ++mt)
    #pragma unroll
    for (int nt = 0; nt < 8; ++nt)
      acc[mt][nt] = (f32x4){0.f, 0.f, 0.f, 0.f};

  const int colb = (lane >> 4) * 8;
  #pragma unroll
  for (int ks = 0; ks < 4; ++ks) {
    #pragma unroll
    for (int nt = 0; nt < 8; ++nt) {
      const bf16x8 bfr = *(const bf16x8*)&vt[(nt * 16 + (lane & 15)) * VT_LD + ks * 32 + colb];
      acc[0][nt] = __builtin_amdgcn_mfma_f32_16x16x32_bf16(afr[0][ks], bfr, acc[0][nt], 0, 0, 0);
      acc[1][nt] = __builtin_amdgcn_mfma_f32_16x16x32_bf16(afr[1][ks], bfr, acc[1][nt], 0, 0, 0);
    }
  }

  #pragma unroll
  for (int mt = 0; mt < 2; ++mt)
    #pragma unroll
    for (int nt = 0; nt < 8; ++nt) {
      const int rowm = w * 32 + mt * 16 + (lane >> 4) * 4;
      #pragma unroll
      for (int j = 0; j < 4; ++j)
        __builtin_nontemporal_store(acc[mt][nt][j],
            &att_base[(size_t)(rowm + j) * DIM + nt * 16 + (lane & 15)]);
    }
}

extern "C" void kernel_launch(void* const* d_in, const int* in_sizes, int n_in,
                              void* d_out, int out_size, void* d_ws, size_t ws_size,
                              hipStream_t stream) {
  const int* ssent = (const int*)d_in[0];
  const int* tsent = (const int*)d_in[1];
  const int* smask = (const int*)d_in[2];
  const int* tmask = (const int*)d_in[3];
  const float* semb = (const float*)d_in[4];
  const float* temb = (const float*)d_in[5];
  float* out = (float*)d_out;
  u16* ws16 = (u16*)d_ws;
  const int use_ws = (ws_size >= WS_NEEDED) ? 1 : 0;
  const int use_p16 = (ws_size >= WS_P_NEEDED) ? 1 : 0;

  hipLaunchKernelGGL(pool_kernel, dim3(65536), dim3(256), 0, stream,
                     ssent, tsent, semb, temb, out, ws16, use_ws);
  hipLaunchKernelGGL(score_kernel, dim3(256), dim3(512), 0, stream,
                     smask, tmask, out, ws16, use_ws, use_p16);
  hipLaunchKernelGGL(pv_kernel, dim3(4096), dim3(256), 0, stream, out, ws16, use_ws, use_p16);
}

// Round 8
// 253.624 us; speedup vs baseline: 1.7552x; 1.0214x over previous
//
#include <hip/hip_runtime.h>
#include <hip/hip_bf16.h>
#include <stdint.h>

// SynAlign R8:
//  K1 pool_kernel : 8192 blocks (XCD-swizzled), 8 output rows per block via rolling
//                   3-row window (10 gathers -> 8 outputs, 1.25x instead of 3x reads);
//                   fp32 out nontemporal, bf16 sidecar cached.
//  K2 score_kernel: 256 blocks x 512 thr, reg-prefetch staging, score once, 4-way
//                   parallel row+col softmax; soft fp32 (nt) + bf16 P sidecar.
//  K3 pv_kernel   : 4096 blocks (XCD-swizzled), att = P @ V; VT_LD=138 makes the
//                   V^T staging ds_write_b16 pattern bank-conflict-free (oct groups
//                   at +0/+8/+16/+24 banks); A-frags from bf16 P sidecar; NT stores.

#define SL 128
#define DIM 1024

#define OFF_S     ((size_t)0)
#define OFF_SATT  ((size_t)33554432)
#define OFF_ATSM  ((size_t)67108864)
#define OFF_T     ((size_t)71303168)
#define OFF_TATT  ((size_t)104857600)
#define OFF_TASM  ((size_t)138412032)
#define SIDE_ELEMS ((size_t)33554432)           // bf16 sidecar elems per side
#define PHALF      ((size_t)4194304)            // elems per bf16 soft matrix
#define WS_NEEDED   ((size_t)134217728)         // s/t sidecar bytes
#define WS_P_NEEDED ((size_t)150994944)         // + P sidecar

typedef short bf16x8 __attribute__((ext_vector_type(8)));
typedef float f32x4 __attribute__((ext_vector_type(4)));
typedef unsigned short u16;

#define CH_LD 40   // K2 chunk row stride (bf16): 32 data + 8 pad
#define SC_LD 136  // score row stride (bf16): 128 data + 8 pad
#define VT_LD 138  // K3 V^T row stride (bf16): 128 data + 10 pad (conflict-free writes)

__device__ __forceinline__ u16 f2bf(float f) {
  union { float f; uint32_t u; } v; v.f = f;
  uint32_t r = (v.u + 0x7FFFu + ((v.u >> 16) & 1u)) >> 16;  // RNE
  return (u16)r;
}
__device__ __forceinline__ float bf2f(u16 h) {
  union { uint32_t u; float f; } v; v.u = ((uint32_t)h) << 16;
  return v.f;
}

// ---------------- K1: gather + avgpool3, 8 rows/block rolling window ----------------
__global__ __launch_bounds__(256) void pool_kernel(
    const int* __restrict__ ssent, const int* __restrict__ tsent,
    const float* __restrict__ semb, const float* __restrict__ temb,
    float* __restrict__ out, u16* __restrict__ ws16, int use_ws)
{
  const int raw = blockIdx.x;
  const int bid = (raw & 7) * 1024 + (raw >> 3);   // XCD swizzle (8192 % 8 == 0)
  const int side = bid >> 12;
  const int rem = bid & 4095;
  const int b = rem >> 4;
  const int l0 = (rem & 15) * 8;
  const int tid = threadIdx.x;

  const int* __restrict__ sent = side ? tsent : ssent;
  const float* __restrict__ emb = side ? temb : semb;
  float* __restrict__ dst0 = out + (side ? OFF_T : OFF_S) + ((size_t)b * SL + l0) * DIM;
  u16* __restrict__ d16_0 = ws16 + (side ? SIDE_ELEMS : 0) + ((size_t)b * SL + l0) * DIM;

  const int sbase = b * SL + l0;
  float4 ePrev, eCur, eNext;
  if (l0 > 0) ePrev = ((const float4*)(emb + (size_t)sent[sbase - 1] * DIM))[tid];
  else        ePrev = (float4){0.f, 0.f, 0.f, 0.f};
  eCur = ((const float4*)(emb + (size_t)sent[sbase] * DIM))[tid];

  #pragma unroll
  for (int i = 0; i < 8; ++i) {
    const int l = l0 + i;
    if (l + 1 < SL)
      eNext = ((const float4*)(emb + (size_t)sent[sbase + i + 1] * DIM))[tid];
    else
      eNext = (float4){0.f, 0.f, 0.f, 0.f};
    const float scl = (l == 0 || l == SL - 1) ? 0.5f : (1.0f / 3.0f);
    f32x4 o;
    o[0] = (ePrev.x + eCur.x + eNext.x) * scl;
    o[1] = (ePrev.y + eCur.y + eNext.y) * scl;
    o[2] = (ePrev.z + eCur.z + eNext.z) * scl;
    o[3] = (ePrev.w + eCur.w + eNext.w) * scl;
    __builtin_nontemporal_store(o, ((f32x4*)(dst0 + (size_t)i * DIM)) + tid);
    if (use_ws) {
      ushort4 h;
      h.x = f2bf(o[0]); h.y = f2bf(o[1]); h.z = f2bf(o[2]); h.w = f2bf(o[3]);
      ((ushort4*)(d16_0 + (size_t)i * DIM))[tid] = h;   // cached: re-read by K2/K3
    }
    ePrev = eCur; eCur = eNext;
  }
}

// ---------------- K2: score (once) + dual softmax ----------------
__global__ __launch_bounds__(512) void score_kernel(
    const int* __restrict__ smask, const int* __restrict__ tmask,
    float* __restrict__ out, u16* __restrict__ ws16, int use_ws, int use_p16)
{
  __shared__ __align__(16) u16 a_chunk[SL * CH_LD];   // t rows
  __shared__ __align__(16) u16 b_chunk[SL * CH_LD];   // s rows
  __shared__ __align__(16) u16 score[SL * SC_LD];     // masked ta_score[t][s]
  __shared__ float part[2][4][SL];                    // 0=row,1=col partials
  __shared__ float rowmax[SL], rowinv[SL], colmax[SL], colinv[SL];
  __shared__ float maskT[SL], maskS[SL];

  const int b = blockIdx.x;
  const int tid = threadIdx.x;
  const int lane = tid & 63;
  const int w = tid >> 6;

  const float* t_base = out + OFF_T + (size_t)b * SL * DIM;
  const float* s_base = out + OFF_S + (size_t)b * SL * DIM;
  float* ta_base = out + OFF_TASM + (size_t)b * SL * SL;
  float* at_base = out + OFF_ATSM + (size_t)b * SL * SL;
  u16* taP = ws16 + 2 * SIDE_ELEMS + (size_t)b * SL * SL;
  u16* atP = ws16 + 2 * SIDE_ELEMS + PHALF + (size_t)b * SL * SL;

  if (tid < SL) maskT[tid] = (tmask[b * SL + tid] != 0) ? 1.0f : 0.0f;
  else if (tid < 2 * SL) maskS[tid - SL] = (smask[b * SL + (tid - SL)] != 0) ? 1.0f : 0.0f;

  f32x4 acc[8];
  #pragma unroll
  for (int nt = 0; nt < 8; ++nt) acc[nt] = (f32x4){0.f, 0.f, 0.f, 0.f};

  const int srow = tid >> 2;        // 0..127
  const int sc8 = tid & 3;          // 0..3
  const size_t a_src = SIDE_ELEMS + ((size_t)b * SL + srow) * DIM + sc8 * 8;  // t
  const size_t b_src = ((size_t)b * SL + srow) * DIM + sc8 * 8;               // s
  u16* const a_dst = &a_chunk[srow * CH_LD + sc8 * 8];
  u16* const b_dst = &b_chunk[srow * CH_LD + sc8 * 8];

  uint4 ra, rb;
  float4 fa0, fa1, fb0, fb1;

  if (use_ws) {
    ra = *(const uint4*)(ws16 + a_src);
    rb = *(const uint4*)(ws16 + b_src);
  } else {
    const float* ap = t_base + (size_t)srow * DIM + sc8 * 8;
    const float* bp = s_base + (size_t)srow * DIM + sc8 * 8;
    fa0 = ((const float4*)ap)[0]; fa1 = ((const float4*)ap)[1];
    fb0 = ((const float4*)bp)[0]; fb1 = ((const float4*)bp)[1];
  }

  for (int c = 0; c < 32; ++c) {
    if (use_ws) {
      *(uint4*)a_dst = ra;
      *(uint4*)b_dst = rb;
    } else {
      bf16x8 ha, hb;
      ha[0]=(short)f2bf(fa0.x); ha[1]=(short)f2bf(fa0.y); ha[2]=(short)f2bf(fa0.z); ha[3]=(short)f2bf(fa0.w);
      ha[4]=(short)f2bf(fa1.x); ha[5]=(short)f2bf(fa1.y); ha[6]=(short)f2bf(fa1.z); ha[7]=(short)f2bf(fa1.w);
      hb[0]=(short)f2bf(fb0.x); hb[1]=(short)f2bf(fb0.y); hb[2]=(short)f2bf(fb0.z); hb[3]=(short)f2bf(fb0.w);
      hb[4]=(short)f2bf(fb1.x); hb[5]=(short)f2bf(fb1.y); hb[6]=(short)f2bf(fb1.z); hb[7]=(short)f2bf(fb1.w);
      *(bf16x8*)a_dst = ha;
      *(bf16x8*)b_dst = hb;
    }
    __syncthreads();

    if (c + 1 < 32) {   // prefetch chunk c+1, hides under ds_read + MFMA
      const int dk = (c + 1) * 32;
      if (use_ws) {
        ra = *(const uint4*)(ws16 + a_src + dk);
        rb = *(const uint4*)(ws16 + b_src + dk);
      } else {
        const float* ap = t_base + (size_t)srow * DIM + dk + sc8 * 8;
        const float* bp = s_base + (size_t)srow * DIM + dk + sc8 * 8;
        fa0 = ((const float4*)ap)[0]; fa1 = ((const float4*)ap)[1];
        fb0 = ((const float4*)bp)[0]; fb1 = ((const float4*)bp)[1];
      }
    }

    const int colb = (lane >> 4) * 8;
    const bf16x8 afr = *(const bf16x8*)&a_chunk[(w * 16 + (lane & 15)) * CH_LD + colb];
    #pragma unroll
    for (int nt = 0; nt < 8; ++nt) {
      const bf16x8 bfr = *(const bf16x8*)&b_chunk[(nt * 16 + (lane & 15)) * CH_LD + colb];
      acc[nt] = __builtin_amdgcn_mfma_f32_16x16x32_bf16(afr, bfr, acc[nt], 0, 0, 0);
    }
    __syncthreads();
  }

  #pragma unroll
  for (int nt = 0; nt < 8; ++nt) {
    const int coln = nt * 16 + (lane & 15);
    const float cm = maskS[coln];
    #pragma unroll
    for (int j = 0; j < 4; ++j) {
      const int rowm = w * 16 + (lane >> 4) * 4 + j;
      const float val = (cm != 0.0f && maskT[rowm] != 0.0f) ? acc[nt][j] : -999.0f;
      score[rowm * SC_LD + coln] = f2bf(val);
    }
  }
  __syncthreads();

  // ---- parallel 4-way softmax stats ----
  const int rc = tid & 127;
  const int q = tid >> 7;
  {
    float mx = -1e30f;
    #pragma unroll
    for (int c8 = 0; c8 < 4; ++c8) {
      const uint4 v = *(const uint4*)&score[rc * SC_LD + q * 32 + c8 * 8];
      mx = fmaxf(mx, fmaxf(bf2f((u16)(v.x & 0xffff)), bf2f((u16)(v.x >> 16))));
      mx = fmaxf(mx, fmaxf(bf2f((u16)(v.y & 0xffff)), bf2f((u16)(v.y >> 16))));
      mx = fmaxf(mx, fmaxf(bf2f((u16)(v.z & 0xffff)), bf2f((u16)(v.z >> 16))));
      mx = fmaxf(mx, fmaxf(bf2f((u16)(v.w & 0xffff)), bf2f((u16)(v.w >> 16))));
    }
    part[0][q][rc] = mx;
    float mc = -1e30f;
    #pragma unroll 8
    for (int r = q * 32; r < q * 32 + 32; ++r)
      mc = fmaxf(mc, bf2f(score[r * SC_LD + rc]));
    part[1][q][rc] = mc;
  }
  __syncthreads();
  if (tid < SL) {
    rowmax[tid] = fmaxf(fmaxf(part[0][0][tid], part[0][1][tid]),
                        fmaxf(part[0][2][tid], part[0][3][tid]));
  } else if (tid < 2 * SL) {
    const int c = tid - SL;
    colmax[c] = fmaxf(fmaxf(part[1][0][c], part[1][1][c]),
                      fmaxf(part[1][2][c], part[1][3][c]));
  }
  __syncthreads();
  {
    const float mR = rowmax[rc];
    float sm = 0.0f;
    #pragma unroll
    for (int c8 = 0; c8 < 4; ++c8) {
      const uint4 v = *(const uint4*)&score[rc * SC_LD + q * 32 + c8 * 8];
      sm += __expf(bf2f((u16)(v.x & 0xffff)) - mR) + __expf(bf2f((u16)(v.x >> 16)) - mR);
      sm += __expf(bf2f((u16)(v.y & 0xffff)) - mR) + __expf(bf2f((u16)(v.y >> 16)) - mR);
      sm += __expf(bf2f((u16)(v.z & 0xffff)) - mR) + __expf(bf2f((u16)(v.z >> 16)) - mR);
      sm += __expf(bf2f((u16)(v.w & 0xffff)) - mR) + __expf(bf2f((u16)(v.w >> 16)) - mR);
    }
    part[0][q][rc] = sm;
    const float mC = colmax[rc];
    float sc = 0.0f;
    #pragma unroll 8
    for (int r = q * 32; r < q * 32 + 32; ++r)
      sc += __expf(bf2f(score[r * SC_LD + rc]) - mC);
    part[1][q][rc] = sc;
  }
  __syncthreads();
  if (tid < SL) {
    rowinv[tid] = 1.0f / (part[0][0][tid] + part[0][1][tid] + part[0][2][tid] + part[0][3][tid]);
  } else if (tid < 2 * SL) {
    const int c = tid - SL;
    colinv[c] = 1.0f / (part[1][0][c] + part[1][1][c] + part[1][2][c] + part[1][3][c]);
  }
  __syncthreads();

  for (int idx = tid; idx < SL * SL; idx += 512) {
    const int r = idx >> 7, c = idx & 127;
    const float tv = __expf(bf2f(score[r * SC_LD + c]) - rowmax[r]) * rowinv[r];
    const float av = __expf(bf2f(score[c * SC_LD + r]) - colmax[r]) * colinv[r];
    __builtin_nontemporal_store(tv, &ta_base[idx]);
    __builtin_nontemporal_store(av, &at_base[idx]);
    if (use_p16) {
      taP[idx] = f2bf(tv);
      atP[idx] = f2bf(av);
    }
  }
}

// ---------------- K3: PV GEMM ----------------
__global__ __launch_bounds__(256) void pv_kernel(
    float* __restrict__ out, u16* __restrict__ ws16, int use_ws, int use_p16)
{
  __shared__ __align__(16) u16 vt[SL * VT_LD];   // V^T [n][k], 35,328 B

  const int raw = blockIdx.x;
  const int bid = (raw & 7) * 512 + (raw >> 3);  // bijective: 4096 % 8 == 0
  const int ntile = bid & 7;
  const int b = (bid >> 3) & 255;
  const int ori = bid >> 11;
  const int tid = threadIdx.x;
  const int lane = tid & 63;
  const int w = tid >> 6;

  const float* p_base = out + (ori ? OFF_ATSM : OFF_TASM) + (size_t)b * SL * SL;
  const u16* p16_base = ws16 + 2 * SIDE_ELEMS + (ori ? PHALF : (size_t)0) + (size_t)b * SL * SL;
  float* att_base = out + (ori ? OFF_TATT : OFF_SATT) + (size_t)b * SL * DIM + ntile * 128;

  // stage V^T tile; VT_LD=138 -> oct groups land at banks +0/+8/+16/+24 (free)
  #pragma unroll
  for (int j = 0; j < 8; ++j) {
    const int idx = tid + j * 256;            // [0,2048): k_low(16) x oct(16) x k_high(8)
    const int k = (idx & 15) | ((idx >> 8) << 4);
    const int oct = (idx >> 4) & 15;
    if (use_ws) {
      const u16* src = ws16 + (ori ? SIDE_ELEMS : 0)
                     + ((size_t)b * SL + k) * DIM + ntile * 128 + oct * 8;
      uint4 v = *(const uint4*)src;
      const u16* ev = (const u16*)&v;
      #pragma unroll
      for (int i = 0; i < 8; ++i) vt[(oct * 8 + i) * VT_LD + k] = ev[i];
    } else {
      const float* src = out + (ori ? OFF_T : OFF_S)
                       + ((size_t)b * SL + k) * DIM + ntile * 128 + oct * 8;
      float4 v0 = ((const float4*)src)[0];
      float4 v1 = ((const float4*)src)[1];
      vt[(oct * 8 + 0) * VT_LD + k] = f2bf(v0.x);
      vt[(oct * 8 + 1) * VT_LD + k] = f2bf(v0.y);
      vt[(oct * 8 + 2) * VT_LD + k] = f2bf(v0.z);
      vt[(oct * 8 + 3) * VT_LD + k] = f2bf(v0.w);
      vt[(oct * 8 + 4) * VT_LD + k] = f2bf(v1.x);
      vt[(oct * 8 + 5) * VT_LD + k] = f2bf(v1.y);
      vt[(oct * 8 + 6) * VT_LD + k] = f2bf(v1.z);
      vt[(oct * 8 + 7) * VT_LD + k] = f2bf(v1.w);
    }
  }

  // A-fragments (P): single 16B bf16 loads from sidecar (L2/L3-hot)
  bf16x8 afr[2][4];
  #pragma unroll
  for (int mt = 0; mt < 2; ++mt) {
    const int m = w * 32 + mt * 16 + (lane & 15);
    #pragma unroll
    for (int ks = 0; ks < 4; ++ks) {
      const int k0 = ks * 32 + (lane >> 4) * 8;
      if (use_p16) {
        afr[mt][ks] = *(const bf16x8*)(p16_base + (size_t)m * SL + k0);
      } else {
        const float* pp = p_base + (size_t)m * SL + k0;
        float4 x0 = ((const float4*)pp)[0];
        float4 x1 = ((const float4*)pp)[1];
        bf16x8 a;
        a[0] = (short)f2bf(x0.x); a[1] = (short)f2bf(x0.y);
        a[2] = (short)f2bf(x0.z); a[3] = (short)f2bf(x0.w);
        a[4] = (short)f2bf(x1.x); a[5] = (short)f2bf(x1.y);
        a[6] = (short)f2bf(x1.z); a[7] = (short)f2bf(x1.w);
        afr[mt][ks] = a;
      }
    }
  }
  __syncthreads();

  f32x4 acc[2][8];
  #pragma unroll
  for (int mt = 0; mt < 2; ++mt)
    #pragma unroll
    for (int nt = 0; nt < 8; ++nt)
      acc[mt][nt] = (f32x4){0.f, 0.f, 0.f, 0.f};

  const int colb = (lane >> 4) * 8;
  #pragma unroll
  for (int ks = 0; ks < 4; ++ks) {
    #pragma unroll
    for (int nt = 0; nt < 8; ++nt) {
      const bf16x8 bfr = *(const bf16x8*)&vt[(nt * 16 + (lane & 15)) * VT_LD + ks * 32 + colb];
      acc[0][nt] = __builtin_amdgcn_mfma_f32_16x16x32_bf16(afr[0][ks], bfr, acc[0][nt], 0, 0, 0);
      acc[1][nt] = __builtin_amdgcn_mfma_f32_16x16x32_bf16(afr[1][ks], bfr, acc[1][nt], 0, 0, 0);
    }
  }

  #pragma unroll
  for (int mt = 0; mt < 2; ++mt)
    #pragma unroll
    for (int nt = 0; nt < 8; ++nt) {
      const int rowm = w * 32 + mt * 16 + (lane >> 4) * 4;
      #pragma unroll
      for (int j = 0; j < 4; ++j)
        __builtin_nontemporal_store(acc[mt][nt][j],
            &att_base[(size_t)(rowm + j) * DIM + nt * 16 + (lane & 15)]);
    }
}

extern "C" void kernel_launch(void* const* d_in, const int* in_sizes, int n_in,
                              void* d_out, int out_size, void* d_ws, size_t ws_size,
                              hipStream_t stream) {
  const int* ssent = (const int*)d_in[0];
  const int* tsent = (const int*)d_in[1];
  const int* smask = (const int*)d_in[2];
  const int* tmask = (const int*)d_in[3];
  const float* semb = (const float*)d_in[4];
  const float* temb = (const float*)d_in[5];
  float* out = (float*)d_out;
  u16* ws16 = (u16*)d_ws;
  const int use_ws = (ws_size >= WS_NEEDED) ? 1 : 0;
  const int use_p16 = (ws_size >= WS_P_NEEDED) ? 1 : 0;

  hipLaunchKernelGGL(pool_kernel, dim3(8192), dim3(256), 0, stream,
                     ssent, tsent, semb, temb, out, ws16, use_ws);
  hipLaunchKernelGGL(score_kernel, dim3(256), dim3(512), 0, stream,
                     smask, tmask, out, ws16, use_ws, use_p16);
  hipLaunchKernelGGL(pv_kernel, dim3(4096), dim3(256), 0, stream, out, ws16, use_ws, use_p16);
}

// Round 9
// 246.010 us; speedup vs baseline: 1.8095x; 1.0310x over previous
//
#include <hip/hip_runtime.h>
#include <hip/hip_bf16.h>
#include <stdint.h>

// SynAlign R9:
//  K1 pool_kernel : 4096 blocks (XCD-swizzled), 16 output rows/block rolling window;
//                   fp32 out nontemporal, bf16 sidecar cached.
//  K2 score_kernel: 256 blocks x 512 thr, dk=64 K-chunks (32 barriers instead of 64),
//                   score LDS overlays the chunk pool; reg-prefetch staging; 4-way
//                   parallel row+col softmax; soft fp32 (nt) + bf16 P sidecar.
//  K3 pv_kernel   : 4096 blocks (XCD-swizzled), att = P @ V; VT_LD=138 conflict-free
//                   staging; A-frags from bf16 P sidecar; NT stores.

#define SL 128
#define DIM 1024

#define OFF_S     ((size_t)0)
#define OFF_SATT  ((size_t)33554432)
#define OFF_ATSM  ((size_t)67108864)
#define OFF_T     ((size_t)71303168)
#define OFF_TATT  ((size_t)104857600)
#define OFF_TASM  ((size_t)138412032)
#define SIDE_ELEMS ((size_t)33554432)           // bf16 sidecar elems per side
#define PHALF      ((size_t)4194304)            // elems per bf16 soft matrix
#define WS_NEEDED   ((size_t)134217728)         // s/t sidecar bytes
#define WS_P_NEEDED ((size_t)150994944)         // + P sidecar

typedef short bf16x8 __attribute__((ext_vector_type(8)));
typedef float f32x4 __attribute__((ext_vector_type(4)));
typedef unsigned short u16;

#define CH2   72   // K2 chunk row stride (bf16): 64 data + 8 pad
#define SC_LD 136  // score row stride (bf16): 128 data + 8 pad
#define VT_LD 138  // K3 V^T row stride (bf16): conflict-free staging writes

__device__ __forceinline__ u16 f2bf(float f) {
  union { float f; uint32_t u; } v; v.f = f;
  uint32_t r = (v.u + 0x7FFFu + ((v.u >> 16) & 1u)) >> 16;  // RNE
  return (u16)r;
}
__device__ __forceinline__ float bf2f(u16 h) {
  union { uint32_t u; float f; } v; v.u = ((uint32_t)h) << 16;
  return v.f;
}

// ---------------- K1: gather + avgpool3, 16 rows/block rolling window ----------------
__global__ __launch_bounds__(256) void pool_kernel(
    const int* __restrict__ ssent, const int* __restrict__ tsent,
    const float* __restrict__ semb, const float* __restrict__ temb,
    float* __restrict__ out, u16* __restrict__ ws16, int use_ws)
{
  const int raw = blockIdx.x;
  const int bid = (raw & 7) * 512 + (raw >> 3);   // XCD swizzle (4096 % 8 == 0)
  const int side = bid >> 11;
  const int rem = bid & 2047;
  const int b = rem >> 3;
  const int l0 = (rem & 7) * 16;
  const int tid = threadIdx.x;

  const int* __restrict__ sent = side ? tsent : ssent;
  const float* __restrict__ emb = side ? temb : semb;
  float* __restrict__ dst0 = out + (side ? OFF_T : OFF_S) + ((size_t)b * SL + l0) * DIM;
  u16* __restrict__ d16_0 = ws16 + (side ? SIDE_ELEMS : 0) + ((size_t)b * SL + l0) * DIM;

  const int sbase = b * SL + l0;
  float4 ePrev, eCur, eNext;
  if (l0 > 0) ePrev = ((const float4*)(emb + (size_t)sent[sbase - 1] * DIM))[tid];
  else        ePrev = (float4){0.f, 0.f, 0.f, 0.f};
  eCur = ((const float4*)(emb + (size_t)sent[sbase] * DIM))[tid];

  #pragma unroll
  for (int i = 0; i < 16; ++i) {
    const int l = l0 + i;
    if (l + 1 < SL)
      eNext = ((const float4*)(emb + (size_t)sent[sbase + i + 1] * DIM))[tid];
    else
      eNext = (float4){0.f, 0.f, 0.f, 0.f};
    const float scl = (l == 0 || l == SL - 1) ? 0.5f : (1.0f / 3.0f);
    f32x4 o;
    o[0] = (ePrev.x + eCur.x + eNext.x) * scl;
    o[1] = (ePrev.y + eCur.y + eNext.y) * scl;
    o[2] = (ePrev.z + eCur.z + eNext.z) * scl;
    o[3] = (ePrev.w + eCur.w + eNext.w) * scl;
    __builtin_nontemporal_store(o, ((f32x4*)(dst0 + (size_t)i * DIM)) + tid);
    if (use_ws) {
      ushort4 h;
      h.x = f2bf(o[0]); h.y = f2bf(o[1]); h.z = f2bf(o[2]); h.w = f2bf(o[3]);
      ((ushort4*)(d16_0 + (size_t)i * DIM))[tid] = h;   // cached: re-read by K2/K3
    }
    ePrev = eCur; eCur = eNext;
  }
}

// ---------------- K2: score (once) + dual softmax, dk=64 ----------------
__global__ __launch_bounds__(512) void score_kernel(
    const int* __restrict__ smask, const int* __restrict__ tmask,
    float* __restrict__ out, u16* __restrict__ ws16, int use_ws, int use_p16)
{
  // chunk pool (36,864 B); score [SL][SC_LD] (34,816 B) OVERLAYS it after the K-loop
  __shared__ __align__(16) u16 chunkpool[2 * SL * CH2];
  __shared__ float part[2][4][SL];
  __shared__ float rowmax[SL], rowinv[SL], colmax[SL], colinv[SL];
  __shared__ float maskT[SL], maskS[SL];

  u16* const a_chunk = chunkpool;             // t rows [SL][CH2]
  u16* const b_chunk = chunkpool + SL * CH2;  // s rows [SL][CH2]
  u16* const score   = chunkpool;             // [SL][SC_LD] after K-loop

  const int b = blockIdx.x;
  const int tid = threadIdx.x;
  const int lane = tid & 63;
  const int w = tid >> 6;

  const float* t_base = out + OFF_T + (size_t)b * SL * DIM;
  const float* s_base = out + OFF_S + (size_t)b * SL * DIM;
  float* ta_base = out + OFF_TASM + (size_t)b * SL * SL;
  float* at_base = out + OFF_ATSM + (size_t)b * SL * SL;
  u16* taP = ws16 + 2 * SIDE_ELEMS + (size_t)b * SL * SL;
  u16* atP = ws16 + 2 * SIDE_ELEMS + PHALF + (size_t)b * SL * SL;

  if (tid < SL) maskT[tid] = (tmask[b * SL + tid] != 0) ? 1.0f : 0.0f;
  else if (tid < 2 * SL) maskS[tid - SL] = (smask[b * SL + (tid - SL)] != 0) ? 1.0f : 0.0f;

  f32x4 acc[8];
  #pragma unroll
  for (int nt = 0; nt < 8; ++nt) acc[nt] = (f32x4){0.f, 0.f, 0.f, 0.f};

  // staging: thread owns row srow, 8-col segment seg, for both 32-col halves c=0,1
  const int srow = tid >> 2;        // 0..127
  const int seg = tid & 3;          // 0..3
  const size_t a_src = SIDE_ELEMS + ((size_t)b * SL + srow) * DIM + seg * 8;  // t
  const size_t b_src = ((size_t)b * SL + srow) * DIM + seg * 8;               // s
  u16* const a_dst = &a_chunk[srow * CH2 + seg * 8];
  u16* const b_dst = &b_chunk[srow * CH2 + seg * 8];

  uint4 ra0, ra1, rb0, rb1;   // ws prefetch regs (two 32-col halves per matrix)

  if (use_ws) {
    ra0 = *(const uint4*)(ws16 + a_src);
    ra1 = *(const uint4*)(ws16 + a_src + 32);
    rb0 = *(const uint4*)(ws16 + b_src);
    rb1 = *(const uint4*)(ws16 + b_src + 32);
  }

  for (int it = 0; it < 16; ++it) {
    const int dk = it * 64;
    if (use_ws) {
      *(uint4*)a_dst = ra0;
      *(uint4*)(a_dst + 32) = ra1;
      *(uint4*)b_dst = rb0;
      *(uint4*)(b_dst + 32) = rb1;
    } else {
      // fallback: direct fp32 load + cvt (no prefetch)
      #pragma unroll
      for (int c = 0; c < 2; ++c) {
        const float* ap = t_base + (size_t)srow * DIM + dk + c * 32 + seg * 8;
        const float* bp = s_base + (size_t)srow * DIM + dk + c * 32 + seg * 8;
        float4 va0 = ((const float4*)ap)[0], va1 = ((const float4*)ap)[1];
        float4 vb0 = ((const float4*)bp)[0], vb1 = ((const float4*)bp)[1];
        bf16x8 ha, hb;
        ha[0]=(short)f2bf(va0.x); ha[1]=(short)f2bf(va0.y); ha[2]=(short)f2bf(va0.z); ha[3]=(short)f2bf(va0.w);
        ha[4]=(short)f2bf(va1.x); ha[5]=(short)f2bf(va1.y); ha[6]=(short)f2bf(va1.z); ha[7]=(short)f2bf(va1.w);
        hb[0]=(short)f2bf(vb0.x); hb[1]=(short)f2bf(vb0.y); hb[2]=(short)f2bf(vb0.z); hb[3]=(short)f2bf(vb0.w);
        hb[4]=(short)f2bf(vb1.x); hb[5]=(short)f2bf(vb1.y); hb[6]=(short)f2bf(vb1.z); hb[7]=(short)f2bf(vb1.w);
        *(bf16x8*)(a_dst + c * 32) = ha;
        *(bf16x8*)(b_dst + c * 32) = hb;
      }
    }
    __syncthreads();

    if (use_ws && it + 1 < 16) {   // prefetch next chunk, hides under ds_read+MFMA
      const int dk2 = dk + 64;
      ra0 = *(const uint4*)(ws16 + a_src + dk2);
      ra1 = *(const uint4*)(ws16 + a_src + dk2 + 32);
      rb0 = *(const uint4*)(ws16 + b_src + dk2);
      rb1 = *(const uint4*)(ws16 + b_src + dk2 + 32);
    }

    #pragma unroll
    for (int ks = 0; ks < 2; ++ks) {
      const int colb = ks * 32 + (lane >> 4) * 8;
      const bf16x8 afr = *(const bf16x8*)&a_chunk[(w * 16 + (lane & 15)) * CH2 + colb];
      #pragma unroll
      for (int nt = 0; nt < 8; ++nt) {
        const bf16x8 bfr = *(const bf16x8*)&b_chunk[(nt * 16 + (lane & 15)) * CH2 + colb];
        acc[nt] = __builtin_amdgcn_mfma_f32_16x16x32_bf16(afr, bfr, acc[nt], 0, 0, 0);
      }
    }
    __syncthreads();
  }

  // masked score -> LDS (overlays dead chunk pool). col=lane&15, row=(lane>>4)*4+j
  #pragma unroll
  for (int nt = 0; nt < 8; ++nt) {
    const int coln = nt * 16 + (lane & 15);
    const float cm = maskS[coln];
    #pragma unroll
    for (int j = 0; j < 4; ++j) {
      const int rowm = w * 16 + (lane >> 4) * 4 + j;
      const float val = (cm != 0.0f && maskT[rowm] != 0.0f) ? acc[nt][j] : -999.0f;
      score[rowm * SC_LD + coln] = f2bf(val);
    }
  }
  __syncthreads();

  // ---- parallel 4-way softmax stats ----
  const int rc = tid & 127;
  const int q = tid >> 7;
  {
    float mx = -1e30f;
    #pragma unroll
    for (int c8 = 0; c8 < 4; ++c8) {
      const uint4 v = *(const uint4*)&score[rc * SC_LD + q * 32 + c8 * 8];
      mx = fmaxf(mx, fmaxf(bf2f((u16)(v.x & 0xffff)), bf2f((u16)(v.x >> 16))));
      mx = fmaxf(mx, fmaxf(bf2f((u16)(v.y & 0xffff)), bf2f((u16)(v.y >> 16))));
      mx = fmaxf(mx, fmaxf(bf2f((u16)(v.z & 0xffff)), bf2f((u16)(v.z >> 16))));
      mx = fmaxf(mx, fmaxf(bf2f((u16)(v.w & 0xffff)), bf2f((u16)(v.w >> 16))));
    }
    part[0][q][rc] = mx;
    float mc = -1e30f;
    #pragma unroll 8
    for (int r = q * 32; r < q * 32 + 32; ++r)
      mc = fmaxf(mc, bf2f(score[r * SC_LD + rc]));
    part[1][q][rc] = mc;
  }
  __syncthreads();
  if (tid < SL) {
    rowmax[tid] = fmaxf(fmaxf(part[0][0][tid], part[0][1][tid]),
                        fmaxf(part[0][2][tid], part[0][3][tid]));
  } else if (tid < 2 * SL) {
    const int c = tid - SL;
    colmax[c] = fmaxf(fmaxf(part[1][0][c], part[1][1][c]),
                      fmaxf(part[1][2][c], part[1][3][c]));
  }
  __syncthreads();
  {
    const float mR = rowmax[rc];
    float sm = 0.0f;
    #pragma unroll
    for (int c8 = 0; c8 < 4; ++c8) {
      const uint4 v = *(const uint4*)&score[rc * SC_LD + q * 32 + c8 * 8];
      sm += __expf(bf2f((u16)(v.x & 0xffff)) - mR) + __expf(bf2f((u16)(v.x >> 16)) - mR);
      sm += __expf(bf2f((u16)(v.y & 0xffff)) - mR) + __expf(bf2f((u16)(v.y >> 16)) - mR);
      sm += __expf(bf2f((u16)(v.z & 0xffff)) - mR) + __expf(bf2f((u16)(v.z >> 16)) - mR);
      sm += __expf(bf2f((u16)(v.w & 0xffff)) - mR) + __expf(bf2f((u16)(v.w >> 16)) - mR);
    }
    part[0][q][rc] = sm;
    const float mC = colmax[rc];
    float sc = 0.0f;
    #pragma unroll 8
    for (int r = q * 32; r < q * 32 + 32; ++r)
      sc += __expf(bf2f(score[r * SC_LD + rc]) - mC);
    part[1][q][rc] = sc;
  }
  __syncthreads();
  if (tid < SL) {
    rowinv[tid] = 1.0f / (part[0][0][tid] + part[0][1][tid] + part[0][2][tid] + part[0][3][tid]);
  } else if (tid < 2 * SL) {
    const int c = tid - SL;
    colinv[c] = 1.0f / (part[1][0][c] + part[1][1][c] + part[1][2][c] + part[1][3][c]);
  }
  __syncthreads();

  for (int idx = tid; idx < SL * SL; idx += 512) {
    const int r = idx >> 7, c = idx & 127;
    const float tv = __expf(bf2f(score[r * SC_LD + c]) - rowmax[r]) * rowinv[r];
    const float av = __expf(bf2f(score[c * SC_LD + r]) - colmax[r]) * colinv[r];
    __builtin_nontemporal_store(tv, &ta_base[idx]);
    __builtin_nontemporal_store(av, &at_base[idx]);
    if (use_p16) {
      taP[idx] = f2bf(tv);
      atP[idx] = f2bf(av);
    }
  }
}

// ---------------- K3: PV GEMM ----------------
__global__ __launch_bounds__(256) void pv_kernel(
    float* __restrict__ out, u16* __restrict__ ws16, int use_ws, int use_p16)
{
  __shared__ __align__(16) u16 vt[SL * VT_LD];   // V^T [n][k], 35,328 B

  const int raw = blockIdx.x;
  const int bid = (raw & 7) * 512 + (raw >> 3);  // bijective: 4096 % 8 == 0
  const int ntile = bid & 7;
  const int b = (bid >> 3) & 255;
  const int ori = bid >> 11;
  const int tid = threadIdx.x;
  const int lane = tid & 63;
  const int w = tid >> 6;

  const float* p_base = out + (ori ? OFF_ATSM : OFF_TASM) + (size_t)b * SL * SL;
  const u16* p16_base = ws16 + 2 * SIDE_ELEMS + (ori ? PHALF : (size_t)0) + (size_t)b * SL * SL;
  float* att_base = out + (ori ? OFF_TATT : OFF_SATT) + (size_t)b * SL * DIM + ntile * 128;

  // stage V^T tile; VT_LD=138 -> oct groups at banks +0/+8/+16/+24 (free)
  #pragma unroll
  for (int j = 0; j < 8; ++j) {
    const int idx = tid + j * 256;
    const int k = (idx & 15) | ((idx >> 8) << 4);
    const int oct = (idx >> 4) & 15;
    if (use_ws) {
      const u16* src = ws16 + (ori ? SIDE_ELEMS : 0)
                     + ((size_t)b * SL + k) * DIM + ntile * 128 + oct * 8;
      uint4 v = *(const uint4*)src;
      const u16* ev = (const u16*)&v;
      #pragma unroll
      for (int i = 0; i < 8; ++i) vt[(oct * 8 + i) * VT_LD + k] = ev[i];
    } else {
      const float* src = out + (ori ? OFF_T : OFF_S)
                       + ((size_t)b * SL + k) * DIM + ntile * 128 + oct * 8;
      float4 v0 = ((const float4*)src)[0];
      float4 v1 = ((const float4*)src)[1];
      vt[(oct * 8 + 0) * VT_LD + k] = f2bf(v0.x);
      vt[(oct * 8 + 1) * VT_LD + k] = f2bf(v0.y);
      vt[(oct * 8 + 2) * VT_LD + k] = f2bf(v0.z);
      vt[(oct * 8 + 3) * VT_LD + k] = f2bf(v0.w);
      vt[(oct * 8 + 4) * VT_LD + k] = f2bf(v1.x);
      vt[(oct * 8 + 5) * VT_LD + k] = f2bf(v1.y);
      vt[(oct * 8 + 6) * VT_LD + k] = f2bf(v1.z);
      vt[(oct * 8 + 7) * VT_LD + k] = f2bf(v1.w);
    }
  }

  // A-fragments (P): single 16B bf16 loads from sidecar (L2/L3-hot)
  bf16x8 afr[2][4];
  #pragma unroll
  for (int mt = 0; mt < 2; ++mt) {
    const int m = w * 32 + mt * 16 + (lane & 15);
    #pragma unroll
    for (int ks = 0; ks < 4; ++ks) {
      const int k0 = ks * 32 + (lane >> 4) * 8;
      if (use_p16) {
        afr[mt][ks] = *(const bf16x8*)(p16_base + (size_t)m * SL + k0);
      } else {
        const float* pp = p_base + (size_t)m * SL + k0;
        float4 x0 = ((const float4*)pp)[0];
        float4 x1 = ((const float4*)pp)[1];
        bf16x8 a;
        a[0] = (short)f2bf(x0.x); a[1] = (short)f2bf(x0.y);
        a[2] = (short)f2bf(x0.z); a[3] = (short)f2bf(x0.w);
        a[4] = (short)f2bf(x1.x); a[5] = (short)f2bf(x1.y);
        a[6] = (short)f2bf(x1.z); a[7] = (short)f2bf(x1.w);
        afr[mt][ks] = a;
      }
    }
  }
  __syncthreads();

  f32x4 acc[2][8];
  #pragma unroll
  for (int mt = 0; mt < 2; ++mt)
    #pragma unroll
    for (int nt = 0; nt < 8; ++nt)
      acc[mt][nt] = (f32x4){0.f, 0.f, 0.f, 0.f};

  const int colb = (lane >> 4) * 8;
  #pragma unroll
  for (int ks = 0; ks < 4; ++ks) {
    #pragma unroll
    for (int nt = 0; nt < 8; ++nt) {
      const bf16x8 bfr = *(const bf16x8*)&vt[(nt * 16 + (lane & 15)) * VT_LD + ks * 32 + colb];
      acc[0][nt] = __builtin_amdgcn_mfma_f32_16x16x32_bf16(afr[0][ks], bfr, acc[0][nt], 0, 0, 0);
      acc[1][nt] = __builtin_amdgcn_mfma_f32_16x16x32_bf16(afr[1][ks], bfr, acc[1][nt], 0, 0, 0);
    }
  }

  #pragma unroll
  for (int mt = 0; mt < 2; ++mt)
    #pragma unroll
    for (int nt = 0; nt < 8; ++nt) {
      const int rowm = w * 32 + mt * 16 + (lane >> 4) * 4;
      #pragma unroll
      for (int j = 0; j < 4; ++j)
        __builtin_nontemporal_store(acc[mt][nt][j],
            &att_base[(size_t)(rowm + j) * DIM + nt * 16 + (lane & 15)]);
    }
}

extern "C" void kernel_launch(void* const* d_in, const int* in_sizes, int n_in,
                              void* d_out, int out_size, void* d_ws, size_t ws_size,
                              hipStream_t stream) {
  const int* ssent = (const int*)d_in[0];
  const int* tsent = (const int*)d_in[1];
  const int* smask = (const int*)d_in[2];
  const int* tmask = (const int*)d_in[3];
  const float* semb = (const float*)d_in[4];
  const float* temb = (const float*)d_in[5];
  float* out = (float*)d_out;
  u16* ws16 = (u16*)d_ws;
  const int use_ws = (ws_size >= WS_NEEDED) ? 1 : 0;
  const int use_p16 = (ws_size >= WS_P_NEEDED) ? 1 : 0;

  hipLaunchKernelGGL(pool_kernel, dim3(4096), dim3(256), 0, stream,
                     ssent, tsent, semb, temb, out, ws16, use_ws);
  hipLaunchKernelGGL(score_kernel, dim3(256), dim3(512), 0, stream,
                     smask, tmask, out, ws16, use_ws, use_p16);
  hipLaunchKernelGGL(pv_kernel, dim3(4096), dim3(256), 0, stream, out, ws16, use_ws, use_p16);
}